// Round 5
// baseline (594.315 us; speedup 1.0000x reference)
//
#include <hip/hip_runtime.h>
#include <hip/hip_bf16.h>
#include <stdint.h>

typedef short s16x8 __attribute__((ext_vector_type(8)));
typedef short s16x4 __attribute__((ext_vector_type(4)));
typedef float f32x4 __attribute__((ext_vector_type(4)));

#define NB 4096
#define KTOT 24576
#define NOUT 512
#define NCH 48

__device__ __forceinline__ short f2bf(float f){
  union { float f; uint32_t u; } x; x.f = f;
  uint32_t r = (x.u + 0x7FFFu + ((x.u >> 16) & 1u)) >> 16;
  return (short)r;
}
__device__ __forceinline__ float bf2f(short s){
  union { uint32_t u; float f; } x; x.u = ((uint32_t)(uint16_t)s) << 16;
  return x.f;
}
__device__ __forceinline__ short f2bf_fast(float x){
  union { __hip_bfloat16 h; short s; } c; c.h = __float2bfloat16(x); return c.s;
}

#define GLOAD16(g, l) __builtin_amdgcn_global_load_lds( \
  (const __attribute__((address_space(1))) void*)(g), \
  (__attribute__((address_space(3))) void*)(l), 16, 0, 0)

// ---------------- kernel 0: column->channel map + zero bn0 accumulators ----
__global__ __launch_bounds__(256) void k_colmap(const int* __restrict__ perm,
                                                int* __restrict__ chmap,
                                                float* __restrict__ statf){
  int q = blockIdx.x * 256 + threadIdx.x;
  if (q < 1024) chmap[perm[q]] = q >> 9;
  if (blockIdx.x == 0 && threadIdx.x < 4) statf[threadIdx.x] = 0.f;
}

// ---------------- kernel 1: bn0 batch stats ------------------------------
__global__ __launch_bounds__(256) void k_bn0(const float* __restrict__ concat,
                                             const int* __restrict__ chmap,
                                             float* __restrict__ statf){
  int t = threadIdx.x;
  float s0=0,q0=0,s1=0,q1=0;
  for (int idx = blockIdx.x*256 + t; idx < NB*1024; idx += gridDim.x*256){
    float v = concat[idx];
    int ch = chmap[idx & 1023];
    if (ch){ s1 += v; q1 += v*v; } else { s0 += v; q0 += v*v; }
  }
  #pragma unroll
  for (int m=1;m<64;m<<=1){
    s0 += __shfl_xor(s0,m); q0 += __shfl_xor(q0,m);
    s1 += __shfl_xor(s1,m); q1 += __shfl_xor(q1,m);
  }
  __shared__ float lb[4][4];
  int wid = t>>6, lane = t&63;
  if (lane==0){ lb[wid][0]=s0; lb[wid][1]=q0; lb[wid][2]=s1; lb[wid][3]=q1; }
  __syncthreads();
  if (t==0){
    float a0=0,a1=0,a2=0,a3=0;
    #pragma unroll
    for (int w=0;w<4;w++){ a0+=lb[w][0]; a1+=lb[w][1]; a2+=lb[w][2]; a3+=lb[w][3]; }
    atomicAdd(&statf[0],a0); atomicAdd(&statf[1],a1);
    atomicAdd(&statf[2],a2); atomicAdd(&statf[3],a3);
  }
}

// ---- kernel 2: cast+transpose fc_W -> wTs[n][k] bf16, 16B-granule-swizzled
// within each 64-elem K-tile: logical granule g (8 bf16) stored at slot
// g ^ (n&7), so linear global_load_lds lands the swizzled layout in LDS.
__global__ __launch_bounds__(256) void k_wcast(const float* __restrict__ fcW,
                                               short* __restrict__ wTs){
  __shared__ float tile[64][65];
  int bid = blockIdx.x;
  int kb = (bid % 384) * 64;
  int nb = (bid / 384) * 64;
  int t = threadIdx.x;
  #pragma unroll
  for (int i=0;i<16;i++){
    int r = i*4 + (t>>6), c = t & 63;
    tile[r][c] = fcW[(size_t)(kb + r)*NOUT + nb + c];
  }
  __syncthreads();
  #pragma unroll
  for (int i=0;i<16;i++){
    int n = i*4 + (t>>6), k = t & 63;
    int nr = nb + n;
    int ks = (((k>>3) ^ (nr&7))<<3) | (k&7);
    wTs[(size_t)nr*KTOT + kb + ks] = f2bf(tile[k][n]);
  }
}

// ---------------- kernel 3: per-sample conv (3 branches) ------------------
__global__ __launch_bounds__(256) void k_conv(
    const float* __restrict__ concat, const int* __restrict__ perm,
    const int* __restrict__ rel,
    const float* __restrict__ f1t, const float* __restrict__ f3t,
    const float* __restrict__ f5t,
    const float* __restrict__ statf,
    const float* __restrict__ bn0g, const float* __restrict__ bn0b,
    short* __restrict__ raw, float* __restrict__ psum, float* __restrict__ psq)
{
  const int b = blockIdx.x;
  const int t = threadIdx.x;
  __shared__ float xn[2*9*9*9];     // padded [2][9][9][9], pad = 0
  __shared__ float filt[448];
  for (int i=t;i<1458;i+=256) xn[i]=0.f;
  int r = rel[b];
  for (int i=t;i<448;i+=256){
    float v;
    if (i < 64)       v = f1t[r*64 + i];
    else if (i < 192) v = f3t[r*128 + (i-64)];
    else              v = f5t[r*256 + (i-192)];
    filt[i]=v;
  }
  __syncthreads();
  const float n0inv = 1.f/(4096.f*512.f);
  float m0 = statf[0]*n0inv, e0 = statf[1]*n0inv;
  float m1 = statf[2]*n0inv, e1 = statf[3]*n0inv;
  float sc0 = bn0g[0]*rsqrtf(e0-m0*m0+1e-5f), sh0 = bn0b[0]-m0*sc0;
  float sc1 = bn0g[1]*rsqrtf(e1-m1*m1+1e-5f), sh1 = bn0b[1]-m1*sc1;
  for (int q=t;q<1024;q+=256){
    int col = perm[q];
    float v = concat[(size_t)b*1024 + col];
    int ch = q>>9, s = q & 511;
    int d = s>>6, h=(s>>3)&7, w=s&7;
    xn[ch*729 + d*81 + h*9 + w] = ch ? v*sc1+sh1 : v*sc0+sh0;
  }
  __syncthreads();

  const int wid = t>>6, lane = t&63;
  const int d = lane>>3, h = lane&7;
  float r00[9], r01[9], r10[9], r11[9], r20[9], r21[9], r30[9], r31[9];
  #pragma unroll
  for (int w9=0;w9<9;w9++){
    int base0 = d*81 + h*9 + w9;
    int base1 = d*81 + (h+1)*9 + w9;
    int base2 = (d+1)*81 + h*9 + w9;
    int base3 = (d+1)*81 + (h+1)*9 + w9;
    r00[w9]=xn[base0];      r01[w9]=xn[729+base0];
    r10[w9]=xn[base1];      r11[w9]=xn[729+base1];
    r20[w9]=xn[base2];      r21[w9]=xn[729+base2];
    r30[w9]=xn[base3];      r31[w9]=xn[729+base3];
  }
  const size_t rawbase = (size_t)b*KTOT;

  auto finish = [&](int c, const float* v){
    float s=0,q=0;
    #pragma unroll
    for (int p=0;p<8;p++){ s += v[p]; q += v[p]*v[p]; }
    #pragma unroll
    for (int m=1;m<64;m<<=1){ s += __shfl_xor(s,m); q += __shfl_xor(q,m); }
    if (lane==0){ psum[c*NB+b]=s; psq[c*NB+b]=q; }
    s16x8 pk;
    #pragma unroll
    for (int p=0;p<8;p++) pk[p] = f2bf_fast(v[p]);
    *reinterpret_cast<s16x8*>(raw + rawbase + (size_t)c*512 + lane*8) = pk;
  };

  #pragma unroll
  for (int i=0;i<4;i++){
    int oc = wid + 4*i;
    float c0=filt[oc*4+0], c1=filt[oc*4+1], c2=filt[oc*4+2], c3=filt[oc*4+3];
    float v[8];
    #pragma unroll
    for (int p=0;p<8;p++)
      v[p] = c0*r00[p]+c1*r00[p+1]+c2*r01[p]+c3*r01[p+1];
    finish(oc, v);
  }
  #pragma unroll
  for (int i=0;i<4;i++){
    int oc = wid + 4*i;
    const float* cf = &filt[64 + oc*8];
    float v[8];
    #pragma unroll
    for (int p=0;p<8;p++)
      v[p] = cf[0]*r00[p]+cf[1]*r00[p+1]+cf[2]*r10[p]+cf[3]*r10[p+1]
           + cf[4]*r01[p]+cf[5]*r01[p+1]+cf[6]*r11[p]+cf[7]*r11[p+1];
    finish(16+oc, v);
  }
  #pragma unroll
  for (int i=0;i<4;i++){
    int oc = wid + 4*i;
    const float* cf = &filt[192 + oc*16];
    float v[8];
    #pragma unroll
    for (int p=0;p<8;p++)
      v[p] = cf[0]*r00[p] +cf[1]*r00[p+1] +cf[2]*r10[p] +cf[3]*r10[p+1]
           + cf[4]*r20[p] +cf[5]*r20[p+1] +cf[6]*r30[p] +cf[7]*r30[p+1]
           + cf[8]*r01[p] +cf[9]*r01[p+1] +cf[10]*r11[p]+cf[11]*r11[p+1]
           + cf[12]*r21[p]+cf[13]*r21[p+1]+cf[14]*r31[p]+cf[15]*r31[p+1];
    finish(32+oc, v);
  }
}

// ---------------- kernel 4: finalize bn1/2/3 scale+shift ------------------
__global__ __launch_bounds__(256) void k_bnstats(
    const float* __restrict__ psum, const float* __restrict__ psq,
    const float* __restrict__ bn1g, const float* __restrict__ bn1b,
    const float* __restrict__ bn2g, const float* __restrict__ bn2b,
    const float* __restrict__ bn3g, const float* __restrict__ bn3b,
    float* __restrict__ statf)
{
  int c = blockIdx.x, t = threadIdx.x;
  float s=0,q=0;
  for (int b=t;b<NB;b+=256){ s += psum[c*NB+b]; q += psq[c*NB+b]; }
  #pragma unroll
  for (int m=1;m<64;m<<=1){ s += __shfl_xor(s,m); q += __shfl_xor(q,m); }
  __shared__ float lb[4][2];
  int wid = t>>6, lane = t&63;
  if (lane==0){ lb[wid][0]=s; lb[wid][1]=q; }
  __syncthreads();
  if (t==0){
    s = lb[0][0]+lb[1][0]+lb[2][0]+lb[3][0];
    q = lb[0][1]+lb[1][1]+lb[2][1]+lb[3][1];
    float n = 4096.f*512.f;
    float mean = s/n, var = q/n - mean*mean;
    const float* g  = c<16 ? bn1g : (c<32 ? bn2g : bn3g);
    const float* bb = c<16 ? bn1b : (c<32 ? bn2b : bn3b);
    int oc = c & 15;
    float sc = g[oc]*rsqrtf(var + 1e-5f);
    statf[16+c] = sc;
    statf[64+c] = bb[oc] - mean*sc;
  }
}

// ---------------- kernel 5: SE gates --------------------------------------
__global__ __launch_bounds__(64) void k_se(
    const float* __restrict__ psum, const float* __restrict__ statf,
    const float* __restrict__ Wsq, const float* __restrict__ bsq,
    const float* __restrict__ W1, const float* __restrict__ b1,
    const float* __restrict__ W2, const float* __restrict__ b2,
    const float* __restrict__ W3, const float* __restrict__ b3,
    float* __restrict__ gates)
{
  int b = blockIdx.x, lane = threadIdx.x;
  __shared__ float pooled[16];
  __shared__ float zq[32];
  if (lane < 16){
    float p = 0.f;
    #pragma unroll
    for (int br=0;br<3;br++){
      int c = br*16 + lane;
      p += psum[c*NB+b]*(1.f/512.f)*statf[16+c] + statf[64+c];
    }
    pooled[lane] = p;
  }
  __syncthreads();
  if (lane < 32){
    float z = bsq[lane];
    #pragma unroll
    for (int oc=0;oc<16;oc++) z += pooled[oc]*Wsq[oc*32+lane];
    zq[lane] = fmaxf(z, 0.f);
  }
  __syncthreads();
  if (lane < 48){
    int br = lane>>4, oc = lane&15;
    const float* W  = br==0 ? W1 : (br==1 ? W2 : W3);
    const float* bb = br==0 ? b1 : (br==1 ? b2 : b3);
    float g = bb[oc];
    #pragma unroll
    for (int r2=0;r2<32;r2++) g += zq[r2]*W[r2*16+oc];
    gates[lane*NB + b] = 1.f/(1.f + expf(-g));
  }
}

// ---------------- kernel 6: fused bn+gate+relu GEMM (split-K=8) -----------
// C[4096,512] = A[4096,24576] @ W[24576,512];  A = relu(raw*scg + shg)
// 256x256 tile, BK=64, 8 waves (2M x 4N). m201-style 8-phase schedule:
// 4 phases per K-tile, each = {ds_reads | stage-issue | BAR | lgkmcnt(0) |
// setprio(1) 16xMFMA setprio(0) | BAR}; counted vmcnt(12)/vmcnt(10) only.
// A-tile register double-buffer: tile T lives in aR[T&1].
__global__ __launch_bounds__(512, 2) void k_gemm(
    const short* __restrict__ raw, const short* __restrict__ wTs,
    const float* __restrict__ scale, const float* __restrict__ shift,
    const float* __restrict__ gates, short* __restrict__ partials)
{
  const int t = threadIdx.x;
  const int bid = blockIdx.x;
  const int sk = bid >> 5, rem = bid & 31;   // 8 sk x (16 m x 2 n)
  const int nblk = rem >> 4, mblk = rem & 15;
  const int b0 = mblk*256, n0 = nblk*256;
  const int kb0 = sk*3072;                   // 48 K-tiles of 64

  __shared__ short Al[2][256*64];            // 32KB per buf, swizzled granules
  __shared__ short Wl[2][256*64];

  const int wid = t>>6, lane = t&63;
  const int wm = wid>>2, wn = wid&3;
  const int fr = lane&15, fkq = lane>>4;
  const int fr7 = fr&7;

  // ---- per-thread A staging ids ----
  const int ar = t>>1, ah = t&1;             // row, granule-half
  const int arow7 = ar & 7;
  const short* aptr = raw + (size_t)(b0+ar)*KTOT + kb0 + ah*32;

  // ---- gate*scale / gate*shift for this block's 6 channels, in regs ----
  float gsc[6], gsh[6];
  #pragma unroll
  for (int c=0;c<6;c++){
    int ch = sk*6 + c;
    float g = gates[(size_t)ch*NB + b0 + ar];
    gsc[c] = scale[ch]*g;
    gsh[c] = shift[ch]*g;
  }
  asm volatile("s_waitcnt vmcnt(0)" ::: "memory");  // clean vmcnt state

  // ---- W staging: wave covers 16 rows per half-tile h ----
  const int wrowbase = (wid>>1)*64 + (wid&1)*16;   // + h*32 + i*8
  const int wsrow = lane>>3, wsg = lane&7;

  f32x4 acc[8][4];
  #pragma unroll
  for (int m=0;m<8;m++)
    #pragma unroll
    for (int n=0;n<4;n++){ f32x4 z = {0.f,0.f,0.f,0.f}; acc[m][n]=z; }

  s16x8 af[4][2], bfr[2][2][2], aR[2][4];

  #define AISSUE(tile, dst) { \
    const short* p_ = aptr + (tile)*64; \
    _Pragma("unroll") \
    for (int i_=0;i_<4;i_++) (dst)[i_] = *reinterpret_cast<const s16x8*>(p_ + i_*8); }

  #define WISSUE(tile, h, Wbuf) { \
    _Pragma("unroll") \
    for (int i_=0;i_<2;i_++){ \
      int rr_ = wrowbase + (h)*32 + i_*8; \
      GLOAD16(wTs + (size_t)(n0+rr_+wsrow)*KTOT + kb0 + (tile)*64 + wsg*8, \
              &(Wbuf)[rr_*64]); } }

  #define XFORM(src, c, An) { \
    float sc_ = gsc[c], sh_ = gsh[c]; \
    _Pragma("unroll") \
    for (int i_=0;i_<4;i_++){ \
      s16x8 av_; \
      _Pragma("unroll") \
      for (int j_=0;j_<8;j_++) av_[j_] = f2bf_fast(fmaxf(bf2f((src)[i_][j_])*sc_+sh_, 0.f)); \
      int slot_ = (ah*4+i_) ^ arow7; \
      *reinterpret_cast<s16x8*>(&(An)[ar*64 + slot_*8]) = av_; } }

  #define RD_A(Ab, mh) { \
    _Pragma("unroll") \
    for (int m_=0;m_<4;m_++){ \
      int row_ = wm*128 + (mh)*64 + m_*16 + fr; \
      _Pragma("unroll") \
      for (int k_=0;k_<2;k_++){ \
        int slot_ = ((k_<<2)|fkq) ^ fr7; \
        af[m_][k_] = *reinterpret_cast<const s16x8*>(&(Ab)[row_*64 + slot_*8]); } } }

  #define RD_B(Wb, nh) { \
    _Pragma("unroll") \
    for (int n_=0;n_<2;n_++){ \
      int row_ = wn*64 + (nh)*32 + n_*16 + fr; \
      _Pragma("unroll") \
      for (int k_=0;k_<2;k_++){ \
        int slot_ = ((k_<<2)|fkq) ^ fr7; \
        bfr[nh][n_][k_] = *reinterpret_cast<const s16x8*>(&(Wb)[row_*64 + slot_*8]); } } }

  #define MMQ(mh, nh) { \
    __builtin_amdgcn_s_setprio(1); \
    _Pragma("unroll") \
    for (int k_=0;k_<2;k_++) \
      _Pragma("unroll") \
      for (int m_=0;m_<4;m_++) \
        _Pragma("unroll") \
        for (int n_=0;n_<2;n_++) \
          acc[(mh)*4+m_][(nh)*2+n_] = __builtin_amdgcn_mfma_f32_16x16x32_bf16( \
            af[m_][k_], bfr[nh][n_][k_], acc[(mh)*4+m_][(nh)*2+n_], 0,0,0); \
    __builtin_amdgcn_s_setprio(0); }

  #define BARRIER __builtin_amdgcn_s_barrier()
  #define LGKM0 asm volatile("s_waitcnt lgkmcnt(0)" ::: "memory")
  #define FENCE asm volatile("" ::: "memory")

  // ---- prologue: stream order A0, W0, [xform A0], A1, W1, A2 ----
  {
    s16x8 aR0[4];
    AISSUE(0, aR0); FENCE;
    WISSUE(0, 0, Wl[0]); WISSUE(0, 1, Wl[0]); FENCE;
    asm volatile("s_waitcnt vmcnt(4)" ::: "memory");     // A0 done
    XFORM(aR0, 0, Al[0]); FENCE;
    AISSUE(1, aR[1]); FENCE;                             // A(1) -> aR[1]
    WISSUE(1, 0, Wl[1]); WISSUE(1, 1, Wl[1]); FENCE;
    AISSUE(2, aR[0]); FENCE;                             // A(2) -> aR[0]
    LGKM0;
    BARRIER;
  }

  int cur = 0;
  for (int it=0; it<48; ++it){
    short* Ac = Al[cur];
    short* Wc = Wl[cur];
    short* An = Al[cur^1];
    int c1 = (it+1)>>3; c1 = c1>5 ? 5 : c1;   // channel of tile it+1 (clamped)
    const int parity = (it+1)&1;

    // ---- phase 0: quadrant (mh0, nh0) ----
    asm volatile("s_waitcnt vmcnt(12)" ::: "memory");    // W(it) staged
    RD_A(Ac, 0);
    RD_B(Wc, 0);
    BARRIER; LGKM0;
    MMQ(0, 0);
    BARRIER;

    // ---- phase 1: quadrant (mh0, nh1); stage W(it+2).h0; xform A(it+1) ----
    WISSUE(it+2, 0, Wc); FENCE;
    RD_B(Wc, 1);
    asm volatile("s_waitcnt vmcnt(10)" ::: "memory");    // A(it+1) regs ready
    if (parity) { XFORM(aR[1], c1, An); } else { XFORM(aR[0], c1, An); }
    BARRIER; LGKM0;
    MMQ(0, 1);
    BARRIER;

    // ---- phase 2: quadrant (mh1, nh0); stage W(it+2).h1 ----
    WISSUE(it+2, 1, Wc); FENCE;
    RD_A(Ac, 1);
    BARRIER; LGKM0;
    MMQ(1, 0);
    BARRIER;

    // ---- phase 3: quadrant (mh1, nh1); issue A(it+3) -> aR[(it+3)&1] ----
    if (parity) { AISSUE(it+3, aR[1]); } else { AISSUE(it+3, aR[0]); }
    FENCE;
    BARRIER; LGKM0;
    MMQ(1, 1);
    BARRIER;

    cur ^= 1;
  }

  // ---- epilogue: bf16 partials [sk][4096][512] ----
  short* pb = partials + (size_t)sk*NB*NOUT;
  #pragma unroll
  for (int m=0;m<8;m++){
    #pragma unroll
    for (int j=0;j<4;j++){
      int row = b0 + wm*128 + m*16 + fkq*4 + j;
      short* prow = pb + (size_t)row*NOUT + n0 + wn*64 + fr;
      #pragma unroll
      for (int n=0;n<4;n++) prow[n*16] = f2bf_fast(acc[m][n][j]);
    }
  }
  #undef AISSUE
  #undef WISSUE
  #undef XFORM
  #undef RD_A
  #undef RD_B
  #undef MMQ
  #undef BARRIER
  #undef LGKM0
  #undef FENCE
}

// ---------------- kernel 7: split-K reduce + bias -------------------------
__global__ __launch_bounds__(256) void k_red(const short* __restrict__ partials,
                                             const float* __restrict__ fcb,
                                             float* __restrict__ out){
  int i = blockIdx.x*256 + threadIdx.x;          // 524288 threads, 4 outs each
  int base = i*4;
  f32x4 v = *reinterpret_cast<const f32x4*>(fcb + (base & 511));
  #pragma unroll
  for (int sk=0;sk<8;sk++){
    s16x4 p = *reinterpret_cast<const s16x4*>(partials + (size_t)sk*2097152 + base);
    v[0] += bf2f(p[0]); v[1] += bf2f(p[1]);
    v[2] += bf2f(p[2]); v[3] += bf2f(p[3]);
  }
  *reinterpret_cast<f32x4*>(out + base) = v;
}

// ---------------- launch ---------------------------------------------------
extern "C" void kernel_launch(void* const* d_in, const int* in_sizes, int n_in,
                              void* d_out, int out_size, void* d_ws, size_t ws_size,
                              hipStream_t stream) {
  const float* concat = (const float*)d_in[0];
  const int*   rel    = (const int*)  d_in[1];
  const int*   perm   = (const int*)  d_in[2];
  const float* f1t = (const float*)d_in[3];
  const float* f3t = (const float*)d_in[4];
  const float* f5t = (const float*)d_in[5];
  const float* bn0g=(const float*)d_in[6],  *bn0b=(const float*)d_in[7];
  const float* bn1g=(const float*)d_in[8],  *bn1b=(const float*)d_in[9];
  const float* bn2g=(const float*)d_in[10], *bn2b=(const float*)d_in[11];
  const float* bn3g=(const float*)d_in[12], *bn3b=(const float*)d_in[13];
  const float* Wsq=(const float*)d_in[14],  *bsq=(const float*)d_in[15];
  const float* W1=(const float*)d_in[16],   *b1=(const float*)d_in[17];
  const float* W2=(const float*)d_in[18],   *b2=(const float*)d_in[19];
  const float* W3=(const float*)d_in[20],   *b3=(const float*)d_in[21];
  const float* fcW=(const float*)d_in[22],  *fcb=(const float*)d_in[23];
  float* out = (float*)d_out;
  char* ws = (char*)d_ws;

  const size_t off_raw  = 0;                         // 4096*24576*2 = 201326592
  const size_t off_wT   = 201326592;                 // 512*24576*2  = 25165824
  const size_t off_part = 226492416;                 // 8*4096*512*2 = 33554432 (bf16)
  const size_t off_psum = 260046848;                 // 48*4096*4    = 786432
  const size_t off_psq  = 260833280;                 // 786432
  const size_t off_gate = 261619712;                 // 786432
  const size_t off_stat = 262406144;                 // 512
  const size_t off_chm  = 262406656;                 // 4096
  const size_t need     = off_chm + 4096;
  if (ws_size < need) return;  // diagnose: output stays zero -> absmax ~2.86

  short* raw      = (short*)(ws + off_raw);
  short* wTs      = (short*)(ws + off_wT);
  short* partials = (short*)(ws + off_part);
  float* psum     = (float*)(ws + off_psum);
  float* psq      = (float*)(ws + off_psq);
  float* gates    = (float*)(ws + off_gate);
  float* statf    = (float*)(ws + off_stat);
  int*   chmap    = (int*)  (ws + off_chm);

  k_colmap<<<4, 256, 0, stream>>>(perm, chmap, statf);
  k_bn0   <<<2048, 256, 0, stream>>>(concat, chmap, statf);
  k_wcast <<<3072, 256, 0, stream>>>(fcW, wTs);
  k_conv  <<<4096, 256, 0, stream>>>(concat, perm, rel, f1t, f3t, f5t,
                                     statf, bn0g, bn0b, raw, psum, psq);
  k_bnstats<<<48, 256, 0, stream>>>(psum, psq, bn1g, bn1b, bn2g, bn2b,
                                    bn3g, bn3b, statf);
  k_se    <<<4096, 64, 0, stream>>>(psum, statf, Wsq, bsq, W1, b1, W2, b2,
                                    W3, b3, gates);
  k_gemm  <<<256, 512, 0, stream>>>(raw, wTs, statf+16, statf+64, gates, partials);
  k_red   <<<2048, 256, 0, stream>>>(partials, fcb, out);
}

// Round 6
// 537.551 us; speedup vs baseline: 1.1056x; 1.1056x over previous
//
#include <hip/hip_runtime.h>
#include <hip/hip_bf16.h>
#include <stdint.h>

typedef short s16x8 __attribute__((ext_vector_type(8)));
typedef short s16x4 __attribute__((ext_vector_type(4)));
typedef float f32x4 __attribute__((ext_vector_type(4)));

#define NB 4096
#define KTOT 24576
#define NOUT 512
#define NCH 48

__device__ __forceinline__ short f2bf(float f){
  union { float f; uint32_t u; } x; x.f = f;
  uint32_t r = (x.u + 0x7FFFu + ((x.u >> 16) & 1u)) >> 16;
  return (short)r;
}
__device__ __forceinline__ float bf2f(short s){
  union { uint32_t u; float f; } x; x.u = ((uint32_t)(uint16_t)s) << 16;
  return x.f;
}
__device__ __forceinline__ short f2bf_fast(float x){
  union { __hip_bfloat16 h; short s; } c; c.h = __float2bfloat16(x); return c.s;
}

#define GLOAD16(g, l) __builtin_amdgcn_global_load_lds( \
  (const __attribute__((address_space(1))) void*)(g), \
  (__attribute__((address_space(3))) void*)(l), 16, 0, 0)

// ---------------- kernel 0: column->channel map + zero bn0 accumulators ----
__global__ __launch_bounds__(256) void k_colmap(const int* __restrict__ perm,
                                                int* __restrict__ chmap,
                                                float* __restrict__ statf){
  int q = blockIdx.x * 256 + threadIdx.x;
  if (q < 1024) chmap[perm[q]] = q >> 9;
  if (blockIdx.x == 0 && threadIdx.x < 4) statf[threadIdx.x] = 0.f;
}

// ---------------- kernel 1: bn0 batch stats ------------------------------
__global__ __launch_bounds__(256) void k_bn0(const float* __restrict__ concat,
                                             const int* __restrict__ chmap,
                                             float* __restrict__ statf){
  int t = threadIdx.x;
  float s0=0,q0=0,s1=0,q1=0;
  for (int idx = blockIdx.x*256 + t; idx < NB*1024; idx += gridDim.x*256){
    float v = concat[idx];
    int ch = chmap[idx & 1023];
    if (ch){ s1 += v; q1 += v*v; } else { s0 += v; q0 += v*v; }
  }
  #pragma unroll
  for (int m=1;m<64;m<<=1){
    s0 += __shfl_xor(s0,m); q0 += __shfl_xor(q0,m);
    s1 += __shfl_xor(s1,m); q1 += __shfl_xor(q1,m);
  }
  __shared__ float lb[4][4];
  int wid = t>>6, lane = t&63;
  if (lane==0){ lb[wid][0]=s0; lb[wid][1]=q0; lb[wid][2]=s1; lb[wid][3]=q1; }
  __syncthreads();
  if (t==0){
    float a0=0,a1=0,a2=0,a3=0;
    #pragma unroll
    for (int w=0;w<4;w++){ a0+=lb[w][0]; a1+=lb[w][1]; a2+=lb[w][2]; a3+=lb[w][3]; }
    atomicAdd(&statf[0],a0); atomicAdd(&statf[1],a1);
    atomicAdd(&statf[2],a2); atomicAdd(&statf[3],a3);
  }
}

// ---- kernel 2: cast+transpose fc_W -> wTs[n][k] bf16, 16B-granule-swizzled
__global__ __launch_bounds__(256) void k_wcast(const float* __restrict__ fcW,
                                               short* __restrict__ wTs){
  __shared__ float tile[64][65];
  int bid = blockIdx.x;
  int kb = (bid % 384) * 64;
  int nb = (bid / 384) * 64;
  int t = threadIdx.x;
  #pragma unroll
  for (int i=0;i<16;i++){
    int r = i*4 + (t>>6), c = t & 63;
    tile[r][c] = fcW[(size_t)(kb + r)*NOUT + nb + c];
  }
  __syncthreads();
  #pragma unroll
  for (int i=0;i<16;i++){
    int n = i*4 + (t>>6), k = t & 63;
    int nr = nb + n;
    int ks = (((k>>3) ^ (nr&7))<<3) | (k&7);
    wTs[(size_t)nr*KTOT + kb + ks] = f2bf(tile[k][n]);
  }
}

// ---------------- kernel 3: per-sample conv (3 branches) ------------------
__global__ __launch_bounds__(256) void k_conv(
    const float* __restrict__ concat, const int* __restrict__ perm,
    const int* __restrict__ rel,
    const float* __restrict__ f1t, const float* __restrict__ f3t,
    const float* __restrict__ f5t,
    const float* __restrict__ statf,
    const float* __restrict__ bn0g, const float* __restrict__ bn0b,
    short* __restrict__ raw, float* __restrict__ psum, float* __restrict__ psq)
{
  const int b = blockIdx.x;
  const int t = threadIdx.x;
  __shared__ float xn[2*9*9*9];     // padded [2][9][9][9], pad = 0
  __shared__ float filt[448];
  for (int i=t;i<1458;i+=256) xn[i]=0.f;
  int r = rel[b];
  for (int i=t;i<448;i+=256){
    float v;
    if (i < 64)       v = f1t[r*64 + i];
    else if (i < 192) v = f3t[r*128 + (i-64)];
    else              v = f5t[r*256 + (i-192)];
    filt[i]=v;
  }
  __syncthreads();
  const float n0inv = 1.f/(4096.f*512.f);
  float m0 = statf[0]*n0inv, e0 = statf[1]*n0inv;
  float m1 = statf[2]*n0inv, e1 = statf[3]*n0inv;
  float sc0 = bn0g[0]*rsqrtf(e0-m0*m0+1e-5f), sh0 = bn0b[0]-m0*sc0;
  float sc1 = bn0g[1]*rsqrtf(e1-m1*m1+1e-5f), sh1 = bn0b[1]-m1*sc1;
  for (int q=t;q<1024;q+=256){
    int col = perm[q];
    float v = concat[(size_t)b*1024 + col];
    int ch = q>>9, s = q & 511;
    int d = s>>6, h=(s>>3)&7, w=s&7;
    xn[ch*729 + d*81 + h*9 + w] = ch ? v*sc1+sh1 : v*sc0+sh0;
  }
  __syncthreads();

  const int wid = t>>6, lane = t&63;
  const int d = lane>>3, h = lane&7;
  float r00[9], r01[9], r10[9], r11[9], r20[9], r21[9], r30[9], r31[9];
  #pragma unroll
  for (int w9=0;w9<9;w9++){
    int base0 = d*81 + h*9 + w9;
    int base1 = d*81 + (h+1)*9 + w9;
    int base2 = (d+1)*81 + h*9 + w9;
    int base3 = (d+1)*81 + (h+1)*9 + w9;
    r00[w9]=xn[base0];      r01[w9]=xn[729+base0];
    r10[w9]=xn[base1];      r11[w9]=xn[729+base1];
    r20[w9]=xn[base2];      r21[w9]=xn[729+base2];
    r30[w9]=xn[base3];      r31[w9]=xn[729+base3];
  }
  const size_t rawbase = (size_t)b*KTOT;

  auto finish = [&](int c, const float* v){
    float s=0,q=0;
    #pragma unroll
    for (int p=0;p<8;p++){ s += v[p]; q += v[p]*v[p]; }
    #pragma unroll
    for (int m=1;m<64;m<<=1){ s += __shfl_xor(s,m); q += __shfl_xor(q,m); }
    if (lane==0){ psum[c*NB+b]=s; psq[c*NB+b]=q; }
    s16x8 pk;
    #pragma unroll
    for (int p=0;p<8;p++) pk[p] = f2bf_fast(v[p]);
    *reinterpret_cast<s16x8*>(raw + rawbase + (size_t)c*512 + lane*8) = pk;
  };

  #pragma unroll
  for (int i=0;i<4;i++){
    int oc = wid + 4*i;
    float c0=filt[oc*4+0], c1=filt[oc*4+1], c2=filt[oc*4+2], c3=filt[oc*4+3];
    float v[8];
    #pragma unroll
    for (int p=0;p<8;p++)
      v[p] = c0*r00[p]+c1*r00[p+1]+c2*r01[p]+c3*r01[p+1];
    finish(oc, v);
  }
  #pragma unroll
  for (int i=0;i<4;i++){
    int oc = wid + 4*i;
    const float* cf = &filt[64 + oc*8];
    float v[8];
    #pragma unroll
    for (int p=0;p<8;p++)
      v[p] = cf[0]*r00[p]+cf[1]*r00[p+1]+cf[2]*r10[p]+cf[3]*r10[p+1]
           + cf[4]*r01[p]+cf[5]*r01[p+1]+cf[6]*r11[p]+cf[7]*r11[p+1];
    finish(16+oc, v);
  }
  #pragma unroll
  for (int i=0;i<4;i++){
    int oc = wid + 4*i;
    const float* cf = &filt[192 + oc*16];
    float v[8];
    #pragma unroll
    for (int p=0;p<8;p++)
      v[p] = cf[0]*r00[p] +cf[1]*r00[p+1] +cf[2]*r10[p] +cf[3]*r10[p+1]
           + cf[4]*r20[p] +cf[5]*r20[p+1] +cf[6]*r30[p] +cf[7]*r30[p+1]
           + cf[8]*r01[p] +cf[9]*r01[p+1] +cf[10]*r11[p]+cf[11]*r11[p+1]
           + cf[12]*r21[p]+cf[13]*r21[p+1]+cf[14]*r31[p]+cf[15]*r31[p+1];
    finish(32+oc, v);
  }
}

// ---------------- kernel 4: finalize bn1/2/3 scale+shift ------------------
__global__ __launch_bounds__(256) void k_bnstats(
    const float* __restrict__ psum, const float* __restrict__ psq,
    const float* __restrict__ bn1g, const float* __restrict__ bn1b,
    const float* __restrict__ bn2g, const float* __restrict__ bn2b,
    const float* __restrict__ bn3g, const float* __restrict__ bn3b,
    float* __restrict__ statf)
{
  int c = blockIdx.x, t = threadIdx.x;
  float s=0,q=0;
  for (int b=t;b<NB;b+=256){ s += psum[c*NB+b]; q += psq[c*NB+b]; }
  #pragma unroll
  for (int m=1;m<64;m<<=1){ s += __shfl_xor(s,m); q += __shfl_xor(q,m); }
  __shared__ float lb[4][2];
  int wid = t>>6, lane = t&63;
  if (lane==0){ lb[wid][0]=s; lb[wid][1]=q; }
  __syncthreads();
  if (t==0){
    s = lb[0][0]+lb[1][0]+lb[2][0]+lb[3][0];
    q = lb[0][1]+lb[1][1]+lb[2][1]+lb[3][1];
    float n = 4096.f*512.f;
    float mean = s/n, var = q/n - mean*mean;
    const float* g  = c<16 ? bn1g : (c<32 ? bn2g : bn3g);
    const float* bb = c<16 ? bn1b : (c<32 ? bn2b : bn3b);
    int oc = c & 15;
    float sc = g[oc]*rsqrtf(var + 1e-5f);
    statf[16+c] = sc;
    statf[64+c] = bb[oc] - mean*sc;
  }
}

// ---------------- kernel 5: SE gates (thread-per-sample) ------------------
__global__ __launch_bounds__(256) void k_se(
    const float* __restrict__ psum, const float* __restrict__ statf,
    const float* __restrict__ Wsq, const float* __restrict__ bsq,
    const float* __restrict__ W1, const float* __restrict__ b1,
    const float* __restrict__ W2, const float* __restrict__ b2,
    const float* __restrict__ W3, const float* __restrict__ b3,
    float* __restrict__ gates)
{
  int b = blockIdx.x*256 + threadIdx.x;
  float pooled[16];
  #pragma unroll
  for (int oc=0;oc<16;oc++){
    float p = 0.f;
    #pragma unroll
    for (int br=0;br<3;br++){
      int c = br*16 + oc;
      p += psum[c*NB+b]*(1.f/512.f)*statf[16+c] + statf[64+c];
    }
    pooled[oc] = p;
  }
  float zq[32];
  #pragma unroll
  for (int r2=0;r2<32;r2++){
    float z = bsq[r2];
    #pragma unroll
    for (int oc=0;oc<16;oc++) z += pooled[oc]*Wsq[oc*32+r2];
    zq[r2] = fmaxf(z, 0.f);
  }
  #pragma unroll
  for (int br=0;br<3;br++){
    const float* W  = br==0 ? W1 : (br==1 ? W2 : W3);
    const float* bb = br==0 ? b1 : (br==1 ? b2 : b3);
    #pragma unroll
    for (int oc=0;oc<16;oc++){
      float g = bb[oc];
      #pragma unroll
      for (int r2=0;r2<32;r2++) g += zq[r2]*W[r2*16+oc];
      gates[(size_t)(br*16+oc)*NB + b] = 1.f/(1.f + expf(-g));
    }
  }
}

// ---------------- kernel 6: fused bn+gate+relu GEMM (split-K=8) -----------
// C[4096,512] = A[4096,24576] @ W[24576,512];  A = relu(raw*scg + shg)
// 256x256 tile, BK=64, 8 waves (2M x 4N). m201-style 8-phase schedule:
// 4 phases per K-tile, each = {ds_reads | stage-issue | BAR | lgkmcnt(0) |
// setprio(1) 16xMFMA setprio(0) | BAR}; counted vmcnt(12)/vmcnt(10) only.
// gsc/gsh live in LDS (rule #20: NO runtime-indexed register arrays);
// the pair for tile it+1 is prefetched to regs during phase 0.
__global__ __launch_bounds__(512, 2) void k_gemm(
    const short* __restrict__ raw, const short* __restrict__ wTs,
    const float* __restrict__ scale, const float* __restrict__ shift,
    const float* __restrict__ gates, short* __restrict__ partials)
{
  const int t = threadIdx.x;
  const int bid = blockIdx.x;
  const int sk = bid >> 5, rem = bid & 31;   // 8 sk x (16 m x 2 n)
  const int nblk = rem >> 4, mblk = rem & 15;
  const int b0 = mblk*256, n0 = nblk*256;
  const int kb0 = sk*3072;                   // 48 K-tiles of 64

  __shared__ short Al[2][256*64];            // 32KB per buf, swizzled granules
  __shared__ short Wl[2][256*64];
  __shared__ float gscL[6*256];              // gate*scale per (ch,row)
  __shared__ float gshL[6*256];

  const int wid = t>>6, lane = t&63;
  const int wm = wid>>2, wn = wid&3;
  const int fr = lane&15, fkq = lane>>4;
  const int fr7 = fr&7;

  // ---- per-thread A staging ids ----
  const int ar = t>>1, ah = t&1;             // row, granule-half
  const int arow7 = ar & 7;
  const short* aptr = raw + (size_t)(b0+ar)*KTOT + kb0 + ah*32;

  // ---- stage gate*scale / gate*shift table into LDS ----
  for (int i=t; i<1536; i+=512){
    int c = i>>8, r2 = i&255;
    int ch = sk*6 + c;
    float g = gates[(size_t)ch*NB + b0 + r2];
    gscL[i] = scale[ch]*g;
    gshL[i] = shift[ch]*g;
  }
  __syncthreads();                           // drains all counters: clean state

  // ---- W staging: wave covers 16 rows per half-tile h ----
  const int wrowbase = (wid>>1)*64 + (wid&1)*16;   // + h*32 + i*8
  const int wsrow = lane>>3, wsg = lane&7;

  f32x4 acc[8][4];
  #pragma unroll
  for (int m=0;m<8;m++)
    #pragma unroll
    for (int n=0;n<4;n++){ f32x4 z = {0.f,0.f,0.f,0.f}; acc[m][n]=z; }

  s16x8 af[4][2], bfr[2][2][2], aR[2][4];
  float scgN, shgN;                          // transform pair for tile it+1

  #define AISSUE(tile, dst) { \
    const short* p_ = aptr + (tile)*64; \
    _Pragma("unroll") \
    for (int i_=0;i_<4;i_++) (dst)[i_] = *reinterpret_cast<const s16x8*>(p_ + i_*8); }

  #define WISSUE(tile, h, Wbuf) { \
    _Pragma("unroll") \
    for (int i_=0;i_<2;i_++){ \
      int rr_ = wrowbase + (h)*32 + i_*8; \
      GLOAD16(wTs + (size_t)(n0+rr_+wsrow)*KTOT + kb0 + (tile)*64 + wsg*8, \
              &(Wbuf)[rr_*64]); } }

  #define XFORM(src, scg_, shg_, An) { \
    _Pragma("unroll") \
    for (int i_=0;i_<4;i_++){ \
      s16x8 av_; \
      _Pragma("unroll") \
      for (int j_=0;j_<8;j_++) av_[j_] = f2bf_fast(fmaxf(bf2f((src)[i_][j_])*(scg_)+(shg_), 0.f)); \
      int slot_ = (ah*4+i_) ^ arow7; \
      *reinterpret_cast<s16x8*>(&(An)[ar*64 + slot_*8]) = av_; } }

  #define RD_A(Ab, mh) { \
    _Pragma("unroll") \
    for (int m_=0;m_<4;m_++){ \
      int row_ = wm*128 + (mh)*64 + m_*16 + fr; \
      _Pragma("unroll") \
      for (int k_=0;k_<2;k_++){ \
        int slot_ = ((k_<<2)|fkq) ^ fr7; \
        af[m_][k_] = *reinterpret_cast<const s16x8*>(&(Ab)[row_*64 + slot_*8]); } } }

  #define RD_B(Wb, nh) { \
    _Pragma("unroll") \
    for (int n_=0;n_<2;n_++){ \
      int row_ = wn*64 + (nh)*32 + n_*16 + fr; \
      _Pragma("unroll") \
      for (int k_=0;k_<2;k_++){ \
        int slot_ = ((k_<<2)|fkq) ^ fr7; \
        bfr[nh][n_][k_] = *reinterpret_cast<const s16x8*>(&(Wb)[row_*64 + slot_*8]); } } }

  #define MMQ(mh, nh) { \
    __builtin_amdgcn_s_setprio(1); \
    _Pragma("unroll") \
    for (int k_=0;k_<2;k_++) \
      _Pragma("unroll") \
      for (int m_=0;m_<4;m_++) \
        _Pragma("unroll") \
        for (int n_=0;n_<2;n_++) \
          acc[(mh)*4+m_][(nh)*2+n_] = __builtin_amdgcn_mfma_f32_16x16x32_bf16( \
            af[m_][k_], bfr[nh][n_][k_], acc[(mh)*4+m_][(nh)*2+n_], 0,0,0); \
    __builtin_amdgcn_s_setprio(0); }

  #define BARRIER __builtin_amdgcn_s_barrier()
  #define LGKM0 asm volatile("s_waitcnt lgkmcnt(0)" ::: "memory")
  #define FENCE asm volatile("" ::: "memory")

  // ---- prologue: stream order A0, W0, [xform A0], A1, W1, A2 ----
  {
    s16x8 aR0[4];
    AISSUE(0, aR0); FENCE;
    WISSUE(0, 0, Wl[0]); WISSUE(0, 1, Wl[0]); FENCE;
    asm volatile("s_waitcnt vmcnt(4)" ::: "memory");     // A0 done
    const float scg0 = gscL[ar], shg0 = gshL[ar];        // channel 0
    XFORM(aR0, scg0, shg0, Al[0]); FENCE;
    AISSUE(1, aR[1]); FENCE;                             // A(1) -> aR[1]
    WISSUE(1, 0, Wl[1]); WISSUE(1, 1, Wl[1]); FENCE;
    AISSUE(2, aR[0]); FENCE;                             // A(2) -> aR[0]
    LGKM0;
    BARRIER;
  }

  int cur = 0;
  for (int it=0; it<48; ++it){
    short* Ac = Al[cur];
    short* Wc = Wl[cur];
    short* An = Al[cur^1];
    int c1 = (it+1)>>3; c1 = c1>5 ? 5 : c1;   // channel of tile it+1 (clamped)
    const int parity = (it+1)&1;

    // ---- phase 0: quadrant (mh0, nh0); prefetch next scg/shg pair ----
    asm volatile("s_waitcnt vmcnt(12)" ::: "memory");    // W(it) staged
    scgN = gscL[c1*256 + ar];
    shgN = gshL[c1*256 + ar];
    RD_A(Ac, 0);
    RD_B(Wc, 0);
    BARRIER; LGKM0;
    MMQ(0, 0);
    BARRIER;

    // ---- phase 1: quadrant (mh0, nh1); stage W(it+2).h0; xform A(it+1) ----
    WISSUE(it+2, 0, Wc); FENCE;
    RD_B(Wc, 1);
    asm volatile("s_waitcnt vmcnt(10)" ::: "memory");    // A(it+1) regs ready
    if (parity) { XFORM(aR[1], scgN, shgN, An); } else { XFORM(aR[0], scgN, shgN, An); }
    BARRIER; LGKM0;
    MMQ(0, 1);
    BARRIER;

    // ---- phase 2: quadrant (mh1, nh0); stage W(it+2).h1 ----
    WISSUE(it+2, 1, Wc); FENCE;
    RD_A(Ac, 1);
    BARRIER; LGKM0;
    MMQ(1, 0);
    BARRIER;

    // ---- phase 3: quadrant (mh1, nh1); issue A(it+3) -> aR[(it+3)&1] ----
    if (parity) { AISSUE(it+3, aR[1]); } else { AISSUE(it+3, aR[0]); }
    FENCE;
    BARRIER; LGKM0;
    MMQ(1, 1);
    BARRIER;

    cur ^= 1;
  }

  // ---- epilogue: bf16 partials [sk][4096][512] ----
  short* pb = partials + (size_t)sk*NB*NOUT;
  #pragma unroll
  for (int m=0;m<8;m++){
    #pragma unroll
    for (int j=0;j<4;j++){
      int row = b0 + wm*128 + m*16 + fkq*4 + j;
      short* prow = pb + (size_t)row*NOUT + n0 + wn*64 + fr;
      #pragma unroll
      for (int n=0;n<4;n++) prow[n*16] = f2bf_fast(acc[m][n][j]);
    }
  }
  #undef AISSUE
  #undef WISSUE
  #undef XFORM
  #undef RD_A
  #undef RD_B
  #undef MMQ
  #undef BARRIER
  #undef LGKM0
  #undef FENCE
}

// ---------------- kernel 7: split-K reduce + bias -------------------------
__global__ __launch_bounds__(256) void k_red(const short* __restrict__ partials,
                                             const float* __restrict__ fcb,
                                             float* __restrict__ out){
  int i = blockIdx.x*256 + threadIdx.x;          // 524288 threads, 4 outs each
  int base = i*4;
  f32x4 v = *reinterpret_cast<const f32x4*>(fcb + (base & 511));
  #pragma unroll
  for (int sk=0;sk<8;sk++){
    s16x4 p = *reinterpret_cast<const s16x4*>(partials + (size_t)sk*2097152 + base);
    v[0] += bf2f(p[0]); v[1] += bf2f(p[1]);
    v[2] += bf2f(p[2]); v[3] += bf2f(p[3]);
  }
  *reinterpret_cast<f32x4*>(out + base) = v;
}

// ---------------- launch ---------------------------------------------------
extern "C" void kernel_launch(void* const* d_in, const int* in_sizes, int n_in,
                              void* d_out, int out_size, void* d_ws, size_t ws_size,
                              hipStream_t stream) {
  const float* concat = (const float*)d_in[0];
  const int*   rel    = (const int*)  d_in[1];
  const int*   perm   = (const int*)  d_in[2];
  const float* f1t = (const float*)d_in[3];
  const float* f3t = (const float*)d_in[4];
  const float* f5t = (const float*)d_in[5];
  const float* bn0g=(const float*)d_in[6],  *bn0b=(const float*)d_in[7];
  const float* bn1g=(const float*)d_in[8],  *bn1b=(const float*)d_in[9];
  const float* bn2g=(const float*)d_in[10], *bn2b=(const float*)d_in[11];
  const float* bn3g=(const float*)d_in[12], *bn3b=(const float*)d_in[13];
  const float* Wsq=(const float*)d_in[14],  *bsq=(const float*)d_in[15];
  const float* W1=(const float*)d_in[16],   *b1=(const float*)d_in[17];
  const float* W2=(const float*)d_in[18],   *b2=(const float*)d_in[19];
  const float* W3=(const float*)d_in[20],   *b3=(const float*)d_in[21];
  const float* fcW=(const float*)d_in[22],  *fcb=(const float*)d_in[23];
  float* out = (float*)d_out;
  char* ws = (char*)d_ws;

  const size_t off_raw  = 0;                         // 4096*24576*2 = 201326592
  const size_t off_wT   = 201326592;                 // 512*24576*2  = 25165824
  const size_t off_part = 226492416;                 // 8*4096*512*2 = 33554432 (bf16)
  const size_t off_psum = 260046848;                 // 48*4096*4    = 786432
  const size_t off_psq  = 260833280;                 // 786432
  const size_t off_gate = 261619712;                 // 786432
  const size_t off_stat = 262406144;                 // 512
  const size_t off_chm  = 262406656;                 // 4096
  const size_t need     = off_chm + 4096;
  if (ws_size < need) return;  // diagnose: output stays zero -> absmax ~2.86

  short* raw      = (short*)(ws + off_raw);
  short* wTs      = (short*)(ws + off_wT);
  short* partials = (short*)(ws + off_part);
  float* psum     = (float*)(ws + off_psum);
  float* psq      = (float*)(ws + off_psq);
  float* gates    = (float*)(ws + off_gate);
  float* statf    = (float*)(ws + off_stat);
  int*   chmap    = (int*)  (ws + off_chm);

  k_colmap<<<4, 256, 0, stream>>>(perm, chmap, statf);
  k_bn0   <<<2048, 256, 0, stream>>>(concat, chmap, statf);
  k_wcast <<<3072, 256, 0, stream>>>(fcW, wTs);
  k_conv  <<<4096, 256, 0, stream>>>(concat, perm, rel, f1t, f3t, f5t,
                                     statf, bn0g, bn0b, raw, psum, psq);
  k_bnstats<<<48, 256, 0, stream>>>(psum, psq, bn1g, bn1b, bn2g, bn2b,
                                    bn3g, bn3b, statf);
  k_se    <<<16, 256, 0, stream>>>(psum, statf, Wsq, bsq, W1, b1, W2, b2,
                                   W3, b3, gates);
  k_gemm  <<<256, 512, 0, stream>>>(raw, wTs, statf+16, statf+64, gates, partials);
  k_red   <<<2048, 256, 0, stream>>>(partials, fcb, out);
}

// Round 7
// 456.623 us; speedup vs baseline: 1.3015x; 1.1772x over previous
//
#include <hip/hip_runtime.h>
#include <hip/hip_bf16.h>
#include <stdint.h>

typedef short s16x8 __attribute__((ext_vector_type(8)));
typedef short s16x4 __attribute__((ext_vector_type(4)));
typedef float f32x4 __attribute__((ext_vector_type(4)));

#define NB 4096
#define KTOT 24576
#define NOUT 512
#define NCH 48

__device__ __forceinline__ short f2bf(float f){
  union { float f; uint32_t u; } x; x.f = f;
  uint32_t r = (x.u + 0x7FFFu + ((x.u >> 16) & 1u)) >> 16;
  return (short)r;
}
__device__ __forceinline__ float bf2f(short s){
  union { uint32_t u; float f; } x; x.u = ((uint32_t)(uint16_t)s) << 16;
  return x.f;
}
__device__ __forceinline__ short f2bf_fast(float x){
  union { __hip_bfloat16 h; short s; } c; c.h = __float2bfloat16(x); return c.s;
}

#define GLOAD16(g, l) __builtin_amdgcn_global_load_lds( \
  (const __attribute__((address_space(1))) void*)(g), \
  (__attribute__((address_space(3))) void*)(l), 16, 0, 0)

// ---------------- kernel 0: column->channel map + zero bn0 accumulators ----
__global__ __launch_bounds__(256) void k_colmap(const int* __restrict__ perm,
                                                int* __restrict__ chmap,
                                                float* __restrict__ statf){
  int q = blockIdx.x * 256 + threadIdx.x;
  if (q < 1024) chmap[perm[q]] = q >> 9;
  if (blockIdx.x == 0 && threadIdx.x < 4) statf[threadIdx.x] = 0.f;
}

// ---------------- kernel 1: bn0 batch stats (chmap hoisted) ---------------
__global__ __launch_bounds__(256) void k_bn0(const float* __restrict__ concat,
                                             const int* __restrict__ chmap,
                                             float* __restrict__ statf){
  int t = threadIdx.x;
  // grid is 2048 blocks: stride = 2048*256 = 524288 == 0 mod 1024 ->
  // (idx & 1023) is loop-invariant -> one chmap load per thread.
  const int ch = chmap[(blockIdx.x*256 + t) & 1023];
  float s0=0,q0=0,s1=0,q1=0;
  for (int idx = blockIdx.x*256 + t; idx < NB*1024; idx += 2048*256){
    float v = concat[idx];
    if (ch){ s1 += v; q1 += v*v; } else { s0 += v; q0 += v*v; }
  }
  #pragma unroll
  for (int m=1;m<64;m<<=1){
    s0 += __shfl_xor(s0,m); q0 += __shfl_xor(q0,m);
    s1 += __shfl_xor(s1,m); q1 += __shfl_xor(q1,m);
  }
  __shared__ float lb[4][4];
  int wid = t>>6, lane = t&63;
  if (lane==0){ lb[wid][0]=s0; lb[wid][1]=q0; lb[wid][2]=s1; lb[wid][3]=q1; }
  __syncthreads();
  if (t==0){
    float a0=0,a1=0,a2=0,a3=0;
    #pragma unroll
    for (int w=0;w<4;w++){ a0+=lb[w][0]; a1+=lb[w][1]; a2+=lb[w][2]; a3+=lb[w][3]; }
    atomicAdd(&statf[0],a0); atomicAdd(&statf[1],a1);
    atomicAdd(&statf[2],a2); atomicAdd(&statf[3],a3);
  }
}

// ---- kernel 2: cast+transpose fc_W -> wTs[n][k] bf16, 16B-granule-swizzled
__global__ __launch_bounds__(256) void k_wcast(const float* __restrict__ fcW,
                                               short* __restrict__ wTs){
  __shared__ float tile[64][65];
  int bid = blockIdx.x;
  int kb = (bid % 384) * 64;
  int nb = (bid / 384) * 64;
  int t = threadIdx.x;
  #pragma unroll
  for (int i=0;i<16;i++){
    int r = i*4 + (t>>6), c = t & 63;
    tile[r][c] = fcW[(size_t)(kb + r)*NOUT + nb + c];
  }
  __syncthreads();
  #pragma unroll
  for (int i=0;i<16;i++){
    int n = i*4 + (t>>6), k = t & 63;
    int nr = nb + n;
    int ks = (((k>>3) ^ (nr&7))<<3) | (k&7);
    wTs[(size_t)nr*KTOT + kb + ks] = f2bf(tile[k][n]);
  }
}

// ---------------- kernel 3: per-sample conv (3 branches) ------------------
__global__ __launch_bounds__(256) void k_conv(
    const float* __restrict__ concat, const int* __restrict__ perm,
    const int* __restrict__ rel,
    const float* __restrict__ f1t, const float* __restrict__ f3t,
    const float* __restrict__ f5t,
    const float* __restrict__ statf,
    const float* __restrict__ bn0g, const float* __restrict__ bn0b,
    short* __restrict__ raw, float* __restrict__ psum, float* __restrict__ psq)
{
  const int b = blockIdx.x;
  const int t = threadIdx.x;
  __shared__ float xn[2*9*9*9];     // padded [2][9][9][9], pad = 0
  __shared__ float filt[448];
  for (int i=t;i<1458;i+=256) xn[i]=0.f;
  int r = rel[b];
  for (int i=t;i<448;i+=256){
    float v;
    if (i < 64)       v = f1t[r*64 + i];
    else if (i < 192) v = f3t[r*128 + (i-64)];
    else              v = f5t[r*256 + (i-192)];
    filt[i]=v;
  }
  __syncthreads();
  const float n0inv = 1.f/(4096.f*512.f);
  float m0 = statf[0]*n0inv, e0 = statf[1]*n0inv;
  float m1 = statf[2]*n0inv, e1 = statf[3]*n0inv;
  float sc0 = bn0g[0]*rsqrtf(e0-m0*m0+1e-5f), sh0 = bn0b[0]-m0*sc0;
  float sc1 = bn0g[1]*rsqrtf(e1-m1*m1+1e-5f), sh1 = bn0b[1]-m1*sc1;
  for (int q=t;q<1024;q+=256){
    int col = perm[q];
    float v = concat[(size_t)b*1024 + col];
    int ch = q>>9, s = q & 511;
    int d = s>>6, h=(s>>3)&7, w=s&7;
    xn[ch*729 + d*81 + h*9 + w] = ch ? v*sc1+sh1 : v*sc0+sh0;
  }
  __syncthreads();

  const int wid = t>>6, lane = t&63;
  const int d = lane>>3, h = lane&7;
  float r00[9], r01[9], r10[9], r11[9], r20[9], r21[9], r30[9], r31[9];
  #pragma unroll
  for (int w9=0;w9<9;w9++){
    int base0 = d*81 + h*9 + w9;
    int base1 = d*81 + (h+1)*9 + w9;
    int base2 = (d+1)*81 + h*9 + w9;
    int base3 = (d+1)*81 + (h+1)*9 + w9;
    r00[w9]=xn[base0];      r01[w9]=xn[729+base0];
    r10[w9]=xn[base1];      r11[w9]=xn[729+base1];
    r20[w9]=xn[base2];      r21[w9]=xn[729+base2];
    r30[w9]=xn[base3];      r31[w9]=xn[729+base3];
  }
  const size_t rawbase = (size_t)b*KTOT;

  auto finish = [&](int c, const float* v){
    float s=0,q=0;
    #pragma unroll
    for (int p=0;p<8;p++){ s += v[p]; q += v[p]*v[p]; }
    #pragma unroll
    for (int m=1;m<64;m<<=1){ s += __shfl_xor(s,m); q += __shfl_xor(q,m); }
    if (lane==0){ psum[c*NB+b]=s; psq[c*NB+b]=q; }
    s16x8 pk;
    #pragma unroll
    for (int p=0;p<8;p++) pk[p] = f2bf_fast(v[p]);
    *reinterpret_cast<s16x8*>(raw + rawbase + (size_t)c*512 + lane*8) = pk;
  };

  #pragma unroll
  for (int i=0;i<4;i++){
    int oc = wid + 4*i;
    float c0=filt[oc*4+0], c1=filt[oc*4+1], c2=filt[oc*4+2], c3=filt[oc*4+3];
    float v[8];
    #pragma unroll
    for (int p=0;p<8;p++)
      v[p] = c0*r00[p]+c1*r00[p+1]+c2*r01[p]+c3*r01[p+1];
    finish(oc, v);
  }
  #pragma unroll
  for (int i=0;i<4;i++){
    int oc = wid + 4*i;
    const float* cf = &filt[64 + oc*8];
    float v[8];
    #pragma unroll
    for (int p=0;p<8;p++)
      v[p] = cf[0]*r00[p]+cf[1]*r00[p+1]+cf[2]*r10[p]+cf[3]*r10[p+1]
           + cf[4]*r01[p]+cf[5]*r01[p+1]+cf[6]*r11[p]+cf[7]*r11[p+1];
    finish(16+oc, v);
  }
  #pragma unroll
  for (int i=0;i<4;i++){
    int oc = wid + 4*i;
    const float* cf = &filt[192 + oc*16];
    float v[8];
    #pragma unroll
    for (int p=0;p<8;p++)
      v[p] = cf[0]*r00[p] +cf[1]*r00[p+1] +cf[2]*r10[p] +cf[3]*r10[p+1]
           + cf[4]*r20[p] +cf[5]*r20[p+1] +cf[6]*r30[p] +cf[7]*r30[p+1]
           + cf[8]*r01[p] +cf[9]*r01[p+1] +cf[10]*r11[p]+cf[11]*r11[p+1]
           + cf[12]*r21[p]+cf[13]*r21[p+1]+cf[14]*r31[p]+cf[15]*r31[p+1];
    finish(32+oc, v);
  }
}

// ---------------- kernel 4: finalize bn1/2/3 scale+shift ------------------
__global__ __launch_bounds__(256) void k_bnstats(
    const float* __restrict__ psum, const float* __restrict__ psq,
    const float* __restrict__ bn1g, const float* __restrict__ bn1b,
    const float* __restrict__ bn2g, const float* __restrict__ bn2b,
    const float* __restrict__ bn3g, const float* __restrict__ bn3b,
    float* __restrict__ statf)
{
  int c = blockIdx.x, t = threadIdx.x;
  float s=0,q=0;
  for (int b=t;b<NB;b+=256){ s += psum[c*NB+b]; q += psq[c*NB+b]; }
  #pragma unroll
  for (int m=1;m<64;m<<=1){ s += __shfl_xor(s,m); q += __shfl_xor(q,m); }
  __shared__ float lb[4][2];
  int wid = t>>6, lane = t&63;
  if (lane==0){ lb[wid][0]=s; lb[wid][1]=q; }
  __syncthreads();
  if (t==0){
    s = lb[0][0]+lb[1][0]+lb[2][0]+lb[3][0];
    q = lb[0][1]+lb[1][1]+lb[2][1]+lb[3][1];
    float n = 4096.f*512.f;
    float mean = s/n, var = q/n - mean*mean;
    const float* g  = c<16 ? bn1g : (c<32 ? bn2g : bn3g);
    const float* bb = c<16 ? bn1b : (c<32 ? bn2b : bn3b);
    int oc = c & 15;
    float sc = g[oc]*rsqrtf(var + 1e-5f);
    statf[16+c] = sc;
    statf[64+c] = bb[oc] - mean*sc;
  }
}

// ---------------- kernel 5: SE gates (thread-per-sample) ------------------
__global__ __launch_bounds__(256) void k_se(
    const float* __restrict__ psum, const float* __restrict__ statf,
    const float* __restrict__ Wsq, const float* __restrict__ bsq,
    const float* __restrict__ W1, const float* __restrict__ b1,
    const float* __restrict__ W2, const float* __restrict__ b2,
    const float* __restrict__ W3, const float* __restrict__ b3,
    float* __restrict__ gates)
{
  int b = blockIdx.x*256 + threadIdx.x;
  float pooled[16];
  #pragma unroll
  for (int oc=0;oc<16;oc++){
    float p = 0.f;
    #pragma unroll
    for (int br=0;br<3;br++){
      int c = br*16 + oc;
      p += psum[c*NB+b]*(1.f/512.f)*statf[16+c] + statf[64+c];
    }
    pooled[oc] = p;
  }
  float zq[32];
  #pragma unroll
  for (int r2=0;r2<32;r2++){
    float z = bsq[r2];
    #pragma unroll
    for (int oc=0;oc<16;oc++) z += pooled[oc]*Wsq[oc*32+r2];
    zq[r2] = fmaxf(z, 0.f);
  }
  #pragma unroll
  for (int br=0;br<3;br++){
    const float* W  = br==0 ? W1 : (br==1 ? W2 : W3);
    const float* bb = br==0 ? b1 : (br==1 ? b2 : b3);
    #pragma unroll
    for (int oc=0;oc<16;oc++){
      float g = bb[oc];
      #pragma unroll
      for (int r2=0;r2<32;r2++) g += zq[r2]*W[r2*16+oc];
      gates[(size_t)(br*16+oc)*NB + b] = 1.f/(1.f + expf(-g));
    }
  }
}

// ---- kernel 5b: in-place transform raw -> A' = relu(raw*sc+sh)*gate, ----
// stored with 16B-granule swizzle (slot = g ^ (b&7)) so k_gemm's linear
// global_load_lds lands the swizzled layout. Load-all -> syncthreads
// (drains vmcnt across the block) -> write-all makes in-place safe.
__global__ __launch_bounds__(256) void k_xf(short* __restrict__ raw,
                                            const float* __restrict__ scale,
                                            const float* __restrict__ shift,
                                            const float* __restrict__ gates)
{
  const int b = blockIdx.x, t = threadIdx.x;
  __shared__ float sL[NCH], hL[NCH];
  if (t < NCH){
    float g = gates[(size_t)t*NB + b];
    sL[t] = scale[t]*g;
    hL[t] = shift[t]*g;
  }
  __syncthreads();
  s16x8 v[12];
  #pragma unroll
  for (int i=0;i<12;i++)
    v[i] = *reinterpret_cast<const s16x8*>(raw + (size_t)b*KTOT + (t + 256*i)*8);
  __syncthreads();   // all row-b loads retired in every thread
  const int bs = b & 7;
  #pragma unroll
  for (int i=0;i<12;i++){
    int G = t + 256*i;          // granule index, 0..3071
    int ch = G >> 6;
    float sc = sL[ch], sh = hL[ch];
    s16x8 o;
    #pragma unroll
    for (int j=0;j<8;j++)
      o[j] = f2bf_fast(fmaxf(bf2f(v[i][j])*sc + sh, 0.f));
    int kt = G >> 3, gk = G & 7;
    *reinterpret_cast<s16x8*>(raw + (size_t)b*KTOT + kt*64 + ((gk ^ bs)<<3)) = o;
  }
}

// ---------------- kernel 6: pure bf16 GEMM (split-K=8), m201 8-phase ------
// C[4096,512] = A'[4096,24576] @ W[24576,512]; both operands pre-swizzled
// in global memory, staged exclusively via global_load_lds (2 loads/phase),
// 8 phases per 2 K-steps, vmcnt(4) at phases 3/7 ends, lgkm0 at 1/5 ends.
__global__ __launch_bounds__(512, 2) void k_gemm(
    const short* __restrict__ Ax, const short* __restrict__ wTs,
    short* __restrict__ partials)
{
  const int t = threadIdx.x;
  const int bid = blockIdx.x;
  const int sk = bid >> 5, rem = bid & 31;   // 8 sk x (16 m x 2 n)
  const int nblk = rem >> 4, mblk = rem & 15;
  const int b0 = mblk*256, n0 = nblk*256;
  const int kb0 = sk*3072;                   // 48 K-steps of 64

  __shared__ __align__(16) short Al[2][256*64];   // K-step s -> buf s&1
  __shared__ __align__(16) short Wl[2][256*64];

  const int wid = t>>6, lane = t&63;
  const int wm = wid>>2, wn = wid&3;
  const int fr = lane&15, fkq = lane>>4;
  const int fr7 = fr&7;

  const short* abase = Ax  + (size_t)b0*KTOT + kb0;
  const short* wbase = wTs + (size_t)n0*KTOT + kb0;
  const int strow = wid*16;            // + h*128 + j*8; lane covers (>>3, &7)
  const int stlr = lane>>3, stg = lane&7;

  f32x4 acc[8][4];
  #pragma unroll
  for (int m=0;m<8;m++)
    #pragma unroll
    for (int n=0;n<4;n++){ f32x4 z = {0.f,0.f,0.f,0.f}; acc[m][n]=z; }

  s16x8 af[2][4][2], bfr[2][2][2];

  #define STG2(buf, base, tile, h) { \
    _Pragma("unroll") \
    for (int j_=0;j_<2;j_++){ \
      int rb_ = (h)*128 + strow + j_*8; \
      GLOAD16((base) + (size_t)(rb_ + stlr)*KTOT + (size_t)(tile)*64 + stg*8, \
              &(buf)[rb_*64]); } }

  #define RD_AF(Ab, mh) { \
    _Pragma("unroll") \
    for (int m_=0;m_<4;m_++){ \
      int row_ = wm*128 + (mh)*64 + m_*16 + fr; \
      _Pragma("unroll") \
      for (int k_=0;k_<2;k_++){ \
        int slot_ = ((k_<<2)|fkq) ^ fr7; \
        af[mh][m_][k_] = *reinterpret_cast<const s16x8*>(&(Ab)[row_*64 + slot_*8]); } } }

  #define RD_BF(Wb, nh) { \
    _Pragma("unroll") \
    for (int n_=0;n_<2;n_++){ \
      int row_ = wn*64 + (nh)*32 + n_*16 + fr; \
      _Pragma("unroll") \
      for (int k_=0;k_<2;k_++){ \
        int slot_ = ((k_<<2)|fkq) ^ fr7; \
        bfr[nh][n_][k_] = *reinterpret_cast<const s16x8*>(&(Wb)[row_*64 + slot_*8]); } } }

  #define MMQ(mh, nh) { \
    __builtin_amdgcn_s_setprio(1); \
    _Pragma("unroll") \
    for (int k_=0;k_<2;k_++) \
      _Pragma("unroll") \
      for (int m_=0;m_<4;m_++) \
        _Pragma("unroll") \
        for (int n_=0;n_<2;n_++) \
          acc[(mh)*4+m_][(nh)*2+n_] = __builtin_amdgcn_mfma_f32_16x16x32_bf16( \
            af[mh][m_][k_], bfr[nh][n_][k_], acc[(mh)*4+m_][(nh)*2+n_], 0,0,0); \
    __builtin_amdgcn_s_setprio(0); }

  #define BARRIER __builtin_amdgcn_s_barrier()
  #define LGKM0 asm volatile("s_waitcnt lgkmcnt(0)" ::: "memory")
  #define VMC4  asm volatile("s_waitcnt vmcnt(4)" ::: "memory")

  // One K-step = 4 phases. b_=its buffer, ob_=other buffer.
  // wtile staged into Wl[ob_] (phases 0,1); atile staged into Al[b_] (2,3).
  #define KSTEP(b_, ob_, wtile, atile) { \
    RD_AF(Al[b_], 0); RD_BF(Wl[b_], 0); \
    STG2(Wl[ob_], wbase, (wtile), 0); \
    BARRIER; MMQ(0,0); BARRIER; \
    RD_BF(Wl[b_], 1); RD_AF(Al[b_], 1); \
    STG2(Wl[ob_], wbase, (wtile), 1); \
    BARRIER; MMQ(0,1); LGKM0; BARRIER; \
    STG2(Al[b_], abase, (atile), 0); \
    BARRIER; MMQ(1,0); BARRIER; \
    STG2(Al[b_], abase, (atile), 1); \
    BARRIER; MMQ(1,1); VMC4; BARRIER; }

  // ---- prologue: A(0), W(0) -> buf0; A(1) -> buf1 (12 loads) ----
  STG2(Al[0], abase, 0, 0); STG2(Al[0], abase, 0, 1);
  STG2(Wl[0], wbase, 0, 0); STG2(Wl[0], wbase, 0, 1);
  STG2(Al[1], abase, 1, 0); STG2(Al[1], abase, 1, 1);
  VMC4;          // A(0)+W(0) landed (4 newest = A(1))
  BARRIER;       // ... in every wave

  for (int it2=0; it2<24; ++it2){
    KSTEP(0, 1, 2*it2+1, 2*it2+2);    // K-step 2t   (stages W(2t+1), A(2t+2))
    KSTEP(1, 0, 2*it2+2, 2*it2+3);    // K-step 2t+1 (stages W(2t+2), A(2t+3))
  }

  // ---- epilogue: bf16 partials [sk][4096][512] ----
  short* pb = partials + (size_t)sk*NB*NOUT;
  #pragma unroll
  for (int m=0;m<8;m++){
    #pragma unroll
    for (int j=0;j<4;j++){
      int row = b0 + wm*128 + m*16 + fkq*4 + j;
      short* prow = pb + (size_t)row*NOUT + n0 + wn*64 + fr;
      #pragma unroll
      for (int n=0;n<4;n++) prow[n*16] = f2bf_fast(acc[m][n][j]);
    }
  }
  #undef STG2
  #undef RD_AF
  #undef RD_BF
  #undef MMQ
  #undef BARRIER
  #undef LGKM0
  #undef VMC4
  #undef KSTEP
}

// ---------------- kernel 7: split-K reduce + bias -------------------------
__global__ __launch_bounds__(256) void k_red(const short* __restrict__ partials,
                                             const float* __restrict__ fcb,
                                             float* __restrict__ out){
  int i = blockIdx.x*256 + threadIdx.x;          // 524288 threads, 4 outs each
  int base = i*4;
  f32x4 v = *reinterpret_cast<const f32x4*>(fcb + (base & 511));
  #pragma unroll
  for (int sk=0;sk<8;sk++){
    s16x4 p = *reinterpret_cast<const s16x4*>(partials + (size_t)sk*2097152 + base);
    v[0] += bf2f(p[0]); v[1] += bf2f(p[1]);
    v[2] += bf2f(p[2]); v[3] += bf2f(p[3]);
  }
  *reinterpret_cast<f32x4*>(out + base) = v;
}

// ---------------- launch ---------------------------------------------------
extern "C" void kernel_launch(void* const* d_in, const int* in_sizes, int n_in,
                              void* d_out, int out_size, void* d_ws, size_t ws_size,
                              hipStream_t stream) {
  const float* concat = (const float*)d_in[0];
  const int*   rel    = (const int*)  d_in[1];
  const int*   perm   = (const int*)  d_in[2];
  const float* f1t = (const float*)d_in[3];
  const float* f3t = (const float*)d_in[4];
  const float* f5t = (const float*)d_in[5];
  const float* bn0g=(const float*)d_in[6],  *bn0b=(const float*)d_in[7];
  const float* bn1g=(const float*)d_in[8],  *bn1b=(const float*)d_in[9];
  const float* bn2g=(const float*)d_in[10], *bn2b=(const float*)d_in[11];
  const float* bn3g=(const float*)d_in[12], *bn3b=(const float*)d_in[13];
  const float* Wsq=(const float*)d_in[14],  *bsq=(const float*)d_in[15];
  const float* W1=(const float*)d_in[16],   *b1=(const float*)d_in[17];
  const float* W2=(const float*)d_in[18],   *b2=(const float*)d_in[19];
  const float* W3=(const float*)d_in[20],   *b3=(const float*)d_in[21];
  const float* fcW=(const float*)d_in[22],  *fcb=(const float*)d_in[23];
  float* out = (float*)d_out;
  char* ws = (char*)d_ws;

  const size_t off_raw  = 0;                         // 4096*24576*2 = 201326592
  const size_t off_wT   = 201326592;                 // 512*24576*2  = 25165824
  const size_t off_part = 226492416;                 // 8*4096*512*2 = 33554432 (bf16)
  const size_t off_psum = 260046848;                 // 48*4096*4    = 786432
  const size_t off_psq  = 260833280;                 // 786432
  const size_t off_gate = 261619712;                 // 786432
  const size_t off_stat = 262406144;                 // 512
  const size_t off_chm  = 262406656;                 // 4096
  const size_t need     = off_chm + 4096;
  if (ws_size < need) return;  // diagnose: output stays zero -> absmax ~2.86

  short* raw      = (short*)(ws + off_raw);
  short* wTs      = (short*)(ws + off_wT);
  short* partials = (short*)(ws + off_part);
  float* psum     = (float*)(ws + off_psum);
  float* psq      = (float*)(ws + off_psq);
  float* gates    = (float*)(ws + off_gate);
  float* statf    = (float*)(ws + off_stat);
  int*   chmap    = (int*)  (ws + off_chm);

  k_colmap<<<4, 256, 0, stream>>>(perm, chmap, statf);
  k_bn0   <<<2048, 256, 0, stream>>>(concat, chmap, statf);
  k_wcast <<<3072, 256, 0, stream>>>(fcW, wTs);
  k_conv  <<<4096, 256, 0, stream>>>(concat, perm, rel, f1t, f3t, f5t,
                                     statf, bn0g, bn0b, raw, psum, psq);
  k_bnstats<<<48, 256, 0, stream>>>(psum, psq, bn1g, bn1b, bn2g, bn2b,
                                    bn3g, bn3b, statf);
  k_se    <<<16, 256, 0, stream>>>(psum, statf, Wsq, bsq, W1, b1, W2, b2,
                                   W3, b3, gates);
  k_xf    <<<4096, 256, 0, stream>>>(raw, statf+16, statf+64, gates);
  k_gemm  <<<256, 512, 0, stream>>>(raw, wTs, partials);
  k_red   <<<2048, 256, 0, stream>>>(partials, fcb, out);
}

// Round 8
// 447.501 us; speedup vs baseline: 1.3281x; 1.0204x over previous
//
#include <hip/hip_runtime.h>
#include <hip/hip_bf16.h>
#include <stdint.h>

typedef short s16x8 __attribute__((ext_vector_type(8)));
typedef short s16x4 __attribute__((ext_vector_type(4)));
typedef float f32x4 __attribute__((ext_vector_type(4)));

#define NB 4096
#define KTOT 24576
#define NOUT 512
#define NCH 48

__device__ __forceinline__ short f2bf(float f){
  union { float f; uint32_t u; } x; x.f = f;
  uint32_t r = (x.u + 0x7FFFu + ((x.u >> 16) & 1u)) >> 16;
  return (short)r;
}
__device__ __forceinline__ float bf2f(short s){
  union { uint32_t u; float f; } x; x.u = ((uint32_t)(uint16_t)s) << 16;
  return x.f;
}
__device__ __forceinline__ short f2bf_fast(float x){
  union { __hip_bfloat16 h; short s; } c; c.h = __float2bfloat16(x); return c.s;
}

#define GLOAD16(g, l) __builtin_amdgcn_global_load_lds( \
  (const __attribute__((address_space(1))) void*)(g), \
  (__attribute__((address_space(3))) void*)(l), 16, 0, 0)

// ---------------- kernel 0: column->channel map + zero bn0 accumulators ----
__global__ __launch_bounds__(256) void k_colmap(const int* __restrict__ perm,
                                                int* __restrict__ chmap,
                                                float* __restrict__ statf){
  int q = blockIdx.x * 256 + threadIdx.x;
  if (q < 1024) chmap[perm[q]] = q >> 9;
  if (blockIdx.x == 0 && threadIdx.x < 4) statf[threadIdx.x] = 0.f;
}

// ---------------- kernel 1: bn0 batch stats (chmap hoisted) ---------------
__global__ __launch_bounds__(256) void k_bn0(const float* __restrict__ concat,
                                             const int* __restrict__ chmap,
                                             float* __restrict__ statf){
  int t = threadIdx.x;
  const int ch = chmap[(blockIdx.x*256 + t) & 1023];
  float s0=0,q0=0,s1=0,q1=0;
  for (int idx = blockIdx.x*256 + t; idx < NB*1024; idx += 2048*256){
    float v = concat[idx];
    if (ch){ s1 += v; q1 += v*v; } else { s0 += v; q0 += v*v; }
  }
  #pragma unroll
  for (int m=1;m<64;m<<=1){
    s0 += __shfl_xor(s0,m); q0 += __shfl_xor(q0,m);
    s1 += __shfl_xor(s1,m); q1 += __shfl_xor(q1,m);
  }
  __shared__ float lb[4][4];
  int wid = t>>6, lane = t&63;
  if (lane==0){ lb[wid][0]=s0; lb[wid][1]=q0; lb[wid][2]=s1; lb[wid][3]=q1; }
  __syncthreads();
  if (t==0){
    float a0=0,a1=0,a2=0,a3=0;
    #pragma unroll
    for (int w=0;w<4;w++){ a0+=lb[w][0]; a1+=lb[w][1]; a2+=lb[w][2]; a3+=lb[w][3]; }
    atomicAdd(&statf[0],a0); atomicAdd(&statf[1],a1);
    atomicAdd(&statf[2],a2); atomicAdd(&statf[3],a3);
  }
}

// ---- kernel 2: cast+transpose fc_W -> wT[n][k] bf16 (PLAIN layout; the
// swizzle now lives in k_gemm's per-lane global_load_lds source address) ----
__global__ __launch_bounds__(256) void k_wcast(const float* __restrict__ fcW,
                                               short* __restrict__ wT){
  __shared__ float tile[64][65];
  int bid = blockIdx.x;
  int kb = (bid % 384) * 64;
  int nb = (bid / 384) * 64;
  int t = threadIdx.x;
  #pragma unroll
  for (int i=0;i<16;i++){
    int r = i*4 + (t>>6), c = t & 63;
    tile[r][c] = fcW[(size_t)(kb + r)*NOUT + nb + c];
  }
  __syncthreads();
  #pragma unroll
  for (int i=0;i<16;i++){
    int n = i*4 + (t>>6), k = t & 63;
    wT[(size_t)(nb + n)*KTOT + kb + k] = f2bf(tile[k][n]);
  }
}

// ---------------- kernel 3: per-sample conv (3 branches) ------------------
__global__ __launch_bounds__(256) void k_conv(
    const float* __restrict__ concat, const int* __restrict__ perm,
    const int* __restrict__ rel,
    const float* __restrict__ f1t, const float* __restrict__ f3t,
    const float* __restrict__ f5t,
    const float* __restrict__ statf,
    const float* __restrict__ bn0g, const float* __restrict__ bn0b,
    short* __restrict__ raw, float* __restrict__ psum, float* __restrict__ psq)
{
  const int b = blockIdx.x;
  const int t = threadIdx.x;
  __shared__ float xn[2*9*9*9];     // padded [2][9][9][9], pad = 0
  __shared__ float filt[448];
  for (int i=t;i<1458;i+=256) xn[i]=0.f;
  int r = rel[b];
  for (int i=t;i<448;i+=256){
    float v;
    if (i < 64)       v = f1t[r*64 + i];
    else if (i < 192) v = f3t[r*128 + (i-64)];
    else              v = f5t[r*256 + (i-192)];
    filt[i]=v;
  }
  __syncthreads();
  const float n0inv = 1.f/(4096.f*512.f);
  float m0 = statf[0]*n0inv, e0 = statf[1]*n0inv;
  float m1 = statf[2]*n0inv, e1 = statf[3]*n0inv;
  float sc0 = bn0g[0]*rsqrtf(e0-m0*m0+1e-5f), sh0 = bn0b[0]-m0*sc0;
  float sc1 = bn0g[1]*rsqrtf(e1-m1*m1+1e-5f), sh1 = bn0b[1]-m1*sc1;
  for (int q=t;q<1024;q+=256){
    int col = perm[q];
    float v = concat[(size_t)b*1024 + col];
    int ch = q>>9, s = q & 511;
    int d = s>>6, h=(s>>3)&7, w=s&7;
    xn[ch*729 + d*81 + h*9 + w] = ch ? v*sc1+sh1 : v*sc0+sh0;
  }
  __syncthreads();

  const int wid = t>>6, lane = t&63;
  const int d = lane>>3, h = lane&7;
  float r00[9], r01[9], r10[9], r11[9], r20[9], r21[9], r30[9], r31[9];
  #pragma unroll
  for (int w9=0;w9<9;w9++){
    int base0 = d*81 + h*9 + w9;
    int base1 = d*81 + (h+1)*9 + w9;
    int base2 = (d+1)*81 + h*9 + w9;
    int base3 = (d+1)*81 + (h+1)*9 + w9;
    r00[w9]=xn[base0];      r01[w9]=xn[729+base0];
    r10[w9]=xn[base1];      r11[w9]=xn[729+base1];
    r20[w9]=xn[base2];      r21[w9]=xn[729+base2];
    r30[w9]=xn[base3];      r31[w9]=xn[729+base3];
  }
  const size_t rawbase = (size_t)b*KTOT;

  auto finish = [&](int c, const float* v){
    float s=0,q=0;
    #pragma unroll
    for (int p=0;p<8;p++){ s += v[p]; q += v[p]*v[p]; }
    #pragma unroll
    for (int m=1;m<64;m<<=1){ s += __shfl_xor(s,m); q += __shfl_xor(q,m); }
    if (lane==0){ psum[c*NB+b]=s; psq[c*NB+b]=q; }
    s16x8 pk;
    #pragma unroll
    for (int p=0;p<8;p++) pk[p] = f2bf_fast(v[p]);
    *reinterpret_cast<s16x8*>(raw + rawbase + (size_t)c*512 + lane*8) = pk;
  };

  #pragma unroll
  for (int i=0;i<4;i++){
    int oc = wid + 4*i;
    float c0=filt[oc*4+0], c1=filt[oc*4+1], c2=filt[oc*4+2], c3=filt[oc*4+3];
    float v[8];
    #pragma unroll
    for (int p=0;p<8;p++)
      v[p] = c0*r00[p]+c1*r00[p+1]+c2*r01[p]+c3*r01[p+1];
    finish(oc, v);
  }
  #pragma unroll
  for (int i=0;i<4;i++){
    int oc = wid + 4*i;
    const float* cf = &filt[64 + oc*8];
    float v[8];
    #pragma unroll
    for (int p=0;p<8;p++)
      v[p] = cf[0]*r00[p]+cf[1]*r00[p+1]+cf[2]*r10[p]+cf[3]*r10[p+1]
           + cf[4]*r01[p]+cf[5]*r01[p+1]+cf[6]*r11[p]+cf[7]*r11[p+1];
    finish(16+oc, v);
  }
  #pragma unroll
  for (int i=0;i<4;i++){
    int oc = wid + 4*i;
    const float* cf = &filt[192 + oc*16];
    float v[8];
    #pragma unroll
    for (int p=0;p<8;p++)
      v[p] = cf[0]*r00[p] +cf[1]*r00[p+1] +cf[2]*r10[p] +cf[3]*r10[p+1]
           + cf[4]*r20[p] +cf[5]*r20[p+1] +cf[6]*r30[p] +cf[7]*r30[p+1]
           + cf[8]*r01[p] +cf[9]*r01[p+1] +cf[10]*r11[p]+cf[11]*r11[p+1]
           + cf[12]*r21[p]+cf[13]*r21[p+1]+cf[14]*r31[p]+cf[15]*r31[p+1];
    finish(32+oc, v);
  }
}

// ---------------- kernel 4: finalize bn1/2/3 scale+shift ------------------
__global__ __launch_bounds__(256) void k_bnstats(
    const float* __restrict__ psum, const float* __restrict__ psq,
    const float* __restrict__ bn1g, const float* __restrict__ bn1b,
    const float* __restrict__ bn2g, const float* __restrict__ bn2b,
    const float* __restrict__ bn3g, const float* __restrict__ bn3b,
    float* __restrict__ statf)
{
  int c = blockIdx.x, t = threadIdx.x;
  float s=0,q=0;
  for (int b=t;b<NB;b+=256){ s += psum[c*NB+b]; q += psq[c*NB+b]; }
  #pragma unroll
  for (int m=1;m<64;m<<=1){ s += __shfl_xor(s,m); q += __shfl_xor(q,m); }
  __shared__ float lb[4][2];
  int wid = t>>6, lane = t&63;
  if (lane==0){ lb[wid][0]=s; lb[wid][1]=q; }
  __syncthreads();
  if (t==0){
    s = lb[0][0]+lb[1][0]+lb[2][0]+lb[3][0];
    q = lb[0][1]+lb[1][1]+lb[2][1]+lb[3][1];
    float n = 4096.f*512.f;
    float mean = s/n, var = q/n - mean*mean;
    const float* g  = c<16 ? bn1g : (c<32 ? bn2g : bn3g);
    const float* bb = c<16 ? bn1b : (c<32 ? bn2b : bn3b);
    int oc = c & 15;
    float sc = g[oc]*rsqrtf(var + 1e-5f);
    statf[16+c] = sc;
    statf[64+c] = bb[oc] - mean*sc;
  }
}

// ---------------- kernel 5: SE gates (thread-per-sample) ------------------
__global__ __launch_bounds__(256) void k_se(
    const float* __restrict__ psum, const float* __restrict__ statf,
    const float* __restrict__ Wsq, const float* __restrict__ bsq,
    const float* __restrict__ W1, const float* __restrict__ b1,
    const float* __restrict__ W2, const float* __restrict__ b2,
    const float* __restrict__ W3, const float* __restrict__ b3,
    float* __restrict__ gates)
{
  int b = blockIdx.x*256 + threadIdx.x;
  float pooled[16];
  #pragma unroll
  for (int oc=0;oc<16;oc++){
    float p = 0.f;
    #pragma unroll
    for (int br=0;br<3;br++){
      int c = br*16 + oc;
      p += psum[c*NB+b]*(1.f/512.f)*statf[16+c] + statf[64+c];
    }
    pooled[oc] = p;
  }
  float zq[32];
  #pragma unroll
  for (int r2=0;r2<32;r2++){
    float z = bsq[r2];
    #pragma unroll
    for (int oc=0;oc<16;oc++) z += pooled[oc]*Wsq[oc*32+r2];
    zq[r2] = fmaxf(z, 0.f);
  }
  #pragma unroll
  for (int br=0;br<3;br++){
    const float* W  = br==0 ? W1 : (br==1 ? W2 : W3);
    const float* bb = br==0 ? b1 : (br==1 ? b2 : b3);
    #pragma unroll
    for (int oc=0;oc<16;oc++){
      float g = bb[oc];
      #pragma unroll
      for (int r2=0;r2<32;r2++) g += zq[r2]*W[r2*16+oc];
      gates[(size_t)(br*16+oc)*NB + b] = 1.f/(1.f + expf(-g));
    }
  }
}

// ---------------- kernel 6: flatmm-style fused GEMM (split-K=8) -----------
// C[4096,512] = relu(raw*sc+sh)*gate @ W.  BM=128, BN=512 (no A dup!),
// BK=32, 8 waves (2M x 4N, wave 64x128).  Ring-3 LDS both operands, stage
// tile s+2 at step s (2-step slack), ONE vmcnt(5) per step (never 0).
// A transformed in-place in LDS (each lane transforms the 16B it staged).
// XOR swizzle (slot = g ^ (row&3)) applied via per-lane GLOBAL source addr.
__global__ __launch_bounds__(512, 2) void k_gemm(
    const short* __restrict__ raw, const short* __restrict__ wT,
    const float* __restrict__ scale, const float* __restrict__ shift,
    const float* __restrict__ gates, short* __restrict__ partials)
{
  const int t = threadIdx.x;
  const int bid = blockIdx.x;
  const int sk = bid & 7, mblk = bid >> 3;   // sk = XCD id -> W L2-resident
  const int b0 = mblk*128;
  const int kb0 = sk*3072;                   // 96 K-steps of 32

  __shared__ __align__(16) short Al[3][128*32];   // 8 KB per slot
  __shared__ __align__(16) short Wl[3][512*32];   // 32 KB per slot
  __shared__ float gscL[6*128], gshL[6*128];

  const int wid = t>>6, lane = t&63;
  const int wm = wid>>2, wn = wid&3;         // 2M x 4N
  const int fr = lane&15, kq = lane>>4;

  // ---- gate*scale / gate*shift table ----
  for (int i=t;i<768;i+=512){
    int c = i>>7, r = i&127;
    int ch = sk*6 + c;
    float g = gates[(size_t)ch*NB + b0 + r];
    gscL[i] = scale[ch]*g;
    gshL[i] = shift[ch]*g;
  }
  __syncthreads();   // drains everything: clean vmcnt ledger

  // ---- staging addresses (inverse-swizzled global source, linear LDS) ----
  const int row_t = wid*16 + (lane>>2);            // A row this lane stages
  const int gsw = ((lane&3) ^ ((lane>>2)&3))*8;    // swizzled granule (shorts)
  const short* aSrc  = raw + (size_t)(b0+row_t)*KTOT + kb0 + gsw;
  const short* wSrc0 = wT + (size_t)(wid*64 +  0 + (lane>>2))*KTOT + kb0 + gsw;
  const short* wSrc1 = wT + (size_t)(wid*64 + 16 + (lane>>2))*KTOT + kb0 + gsw;
  const short* wSrc2 = wT + (size_t)(wid*64 + 32 + (lane>>2))*KTOT + kb0 + gsw;
  const short* wSrc3 = wT + (size_t)(wid*64 + 48 + (lane>>2))*KTOT + kb0 + gsw;
  const int aDst  = wid*16*32;                     // shorts, wave-uniform
  const int wDst0 = (wid*64 +  0)*32;
  const int wDst1 = (wid*64 + 16)*32;
  const int wDst2 = (wid*64 + 32)*32;
  const int wDst3 = (wid*64 + 48)*32;

  // ---- fragment read byte-offsets (swizzled ds_read) ----
  const int so16 = (kq ^ (fr&3))<<4;
  int afb[4], bfb[8];
  #pragma unroll
  for (int m=0;m<4;m++) afb[m] = (wm*64 + m*16 + fr)*64 + so16;
  #pragma unroll
  for (int n=0;n<8;n++) bfb[n] = (wn*128 + n*16 + fr)*64 + so16;
  const int trb = row_t*32 + (lane&3)*8;           // shorts, in-place xform

  f32x4 acc[4][8];
  #pragma unroll
  for (int m=0;m<4;m++)
    #pragma unroll
    for (int n=0;n<8;n++){ f32x4 z = {0.f,0.f,0.f,0.f}; acc[m][n]=z; }

  #define STAGE(c2, ko_) { \
    GLOAD16(aSrc  + (ko_), &Al[c2][aDst]); \
    GLOAD16(wSrc0 + (ko_), &Wl[c2][wDst0]); \
    GLOAD16(wSrc1 + (ko_), &Wl[c2][wDst1]); \
    GLOAD16(wSrc2 + (ko_), &Wl[c2][wDst2]); \
    GLOAD16(wSrc3 + (ko_), &Wl[c2][wDst3]); }

  #define XF(c1, sv1) { \
    int chl_ = (sv1)>>4; chl_ = chl_>5 ? 5 : chl_; \
    float sc_ = gscL[chl_*128 + row_t], sh_ = gshL[chl_*128 + row_t]; \
    short* p_ = &Al[c1][trb]; \
    s16x8 v_ = *reinterpret_cast<const s16x8*>(p_); \
    s16x8 o_; \
    _Pragma("unroll") \
    for (int j_=0;j_<8;j_++) o_[j_] = f2bf_fast(fmaxf(bf2f(v_[j_])*sc_+sh_, 0.f)); \
    *reinterpret_cast<s16x8*>(p_) = o_; }

  #define VMC5  asm volatile("s_waitcnt vmcnt(5)" ::: "memory")
  #define LGKM0 asm volatile("s_waitcnt lgkmcnt(0)" ::: "memory")
  #define BARRIER __builtin_amdgcn_s_barrier()

  #define STEP(sv, c0, c1, c2) { \
    STAGE(c2, ((sv)+2)*32); \
    s16x8 af_[4], bf_[8]; \
    _Pragma("unroll") \
    for (int m_=0;m_<4;m_++) \
      af_[m_] = *reinterpret_cast<const s16x8*>((const char*)Al[c0] + afb[m_]); \
    _Pragma("unroll") \
    for (int n_=0;n_<8;n_++) \
      bf_[n_] = *reinterpret_cast<const s16x8*>((const char*)Wl[c0] + bfb[n_]); \
    __builtin_amdgcn_s_setprio(1); \
    _Pragma("unroll") \
    for (int m_=0;m_<4;m_++) \
      _Pragma("unroll") \
      for (int n_=0;n_<8;n_++) \
        acc[m_][n_] = __builtin_amdgcn_mfma_f32_16x16x32_bf16( \
          af_[m_], bf_[n_], acc[m_][n_], 0,0,0); \
    __builtin_amdgcn_s_setprio(0); \
    VMC5; \
    BARRIER; \
    XF(c1, (sv)+1); \
    LGKM0; \
    BARRIER; }

  // ---- prologue: A(0),W(0) -> slot0; A(1),W(1) -> slot1 (10 loads) ----
  STAGE(0, 0);
  STAGE(1, 32);
  VMC5;            // oldest 5 = A(0),W(0) landed; A(1),W(1) in flight
  XF(0, 0);        // transform tile 0 (ch 0)
  LGKM0;
  BARRIER;

  for (int i3=0; i3<32; ++i3){
    const int s0 = 3*i3;
    STEP(s0+0, 0, 1, 2);
    STEP(s0+1, 1, 2, 0);
    STEP(s0+2, 2, 0, 1);
  }

  // ---- epilogue: bf16 partials [sk][4096][512] ----
  short* pb = partials + (size_t)sk*NB*NOUT;
  #pragma unroll
  for (int m=0;m<4;m++){
    #pragma unroll
    for (int j=0;j<4;j++){
      int row = b0 + wm*64 + m*16 + kq*4 + j;
      short* prow = pb + (size_t)row*NOUT + wn*128 + fr;
      #pragma unroll
      for (int n=0;n<8;n++) prow[n*16] = f2bf_fast(acc[m][n][j]);
    }
  }
  #undef STAGE
  #undef XF
  #undef VMC5
  #undef LGKM0
  #undef BARRIER
  #undef STEP
}

// ---------------- kernel 7: split-K reduce + bias -------------------------
__global__ __launch_bounds__(256) void k_red(const short* __restrict__ partials,
                                             const float* __restrict__ fcb,
                                             float* __restrict__ out){
  int i = blockIdx.x*256 + threadIdx.x;          // 524288 threads, 4 outs each
  int base = i*4;
  f32x4 v = *reinterpret_cast<const f32x4*>(fcb + (base & 511));
  #pragma unroll
  for (int sk=0;sk<8;sk++){
    s16x4 p = *reinterpret_cast<const s16x4*>(partials + (size_t)sk*2097152 + base);
    v[0] += bf2f(p[0]); v[1] += bf2f(p[1]);
    v[2] += bf2f(p[2]); v[3] += bf2f(p[3]);
  }
  *reinterpret_cast<f32x4*>(out + base) = v;
}

// ---------------- launch ---------------------------------------------------
extern "C" void kernel_launch(void* const* d_in, const int* in_sizes, int n_in,
                              void* d_out, int out_size, void* d_ws, size_t ws_size,
                              hipStream_t stream) {
  const float* concat = (const float*)d_in[0];
  const int*   rel    = (const int*)  d_in[1];
  const int*   perm   = (const int*)  d_in[2];
  const float* f1t = (const float*)d_in[3];
  const float* f3t = (const float*)d_in[4];
  const float* f5t = (const float*)d_in[5];
  const float* bn0g=(const float*)d_in[6],  *bn0b=(const float*)d_in[7];
  const float* bn1g=(const float*)d_in[8],  *bn1b=(const float*)d_in[9];
  const float* bn2g=(const float*)d_in[10], *bn2b=(const float*)d_in[11];
  const float* bn3g=(const float*)d_in[12], *bn3b=(const float*)d_in[13];
  const float* Wsq=(const float*)d_in[14],  *bsq=(const float*)d_in[15];
  const float* W1=(const float*)d_in[16],   *b1=(const float*)d_in[17];
  const float* W2=(const float*)d_in[18],   *b2=(const float*)d_in[19];
  const float* W3=(const float*)d_in[20],   *b3=(const float*)d_in[21];
  const float* fcW=(const float*)d_in[22],  *fcb=(const float*)d_in[23];
  float* out = (float*)d_out;
  char* ws = (char*)d_ws;

  const size_t off_raw  = 0;                         // 4096*24576*2 = 201326592
  const size_t off_wT   = 201326592;                 // 512*24576*2  = 25165824
  const size_t off_part = 226492416;                 // 8*4096*512*2 = 33554432 (bf16)
  const size_t off_psum = 260046848;                 // 48*4096*4    = 786432
  const size_t off_psq  = 260833280;                 // 786432
  const size_t off_gate = 261619712;                 // 786432
  const size_t off_stat = 262406144;                 // 512
  const size_t off_chm  = 262406656;                 // 4096
  const size_t need     = off_chm + 4096;
  if (ws_size < need) return;  // diagnose: output stays zero -> absmax ~2.86

  short* raw      = (short*)(ws + off_raw);
  short* wT       = (short*)(ws + off_wT);
  short* partials = (short*)(ws + off_part);
  float* psum     = (float*)(ws + off_psum);
  float* psq      = (float*)(ws + off_psq);
  float* gates    = (float*)(ws + off_gate);
  float* statf    = (float*)(ws + off_stat);
  int*   chmap    = (int*)  (ws + off_chm);

  k_colmap<<<4, 256, 0, stream>>>(perm, chmap, statf);
  k_bn0   <<<2048, 256, 0, stream>>>(concat, chmap, statf);
  k_wcast <<<3072, 256, 0, stream>>>(fcW, wT);
  k_conv  <<<4096, 256, 0, stream>>>(concat, perm, rel, f1t, f3t, f5t,
                                     statf, bn0g, bn0b, raw, psum, psq);
  k_bnstats<<<48, 256, 0, stream>>>(psum, psq, bn1g, bn1b, bn2g, bn2b,
                                    bn3g, bn3b, statf);
  k_se    <<<16, 256, 0, stream>>>(psum, statf, Wsq, bsq, W1, b1, W2, b2,
                                   W3, b3, gates);
  k_gemm  <<<256, 512, 0, stream>>>(raw, wT, statf+16, statf+64, gates, partials);
  k_red   <<<2048, 256, 0, stream>>>(partials, fcb, out);
}

// Round 9
// 422.220 us; speedup vs baseline: 1.4076x; 1.0599x over previous
//
#include <hip/hip_runtime.h>
#include <hip/hip_bf16.h>
#include <stdint.h>

typedef short s16x8 __attribute__((ext_vector_type(8)));
typedef short s16x4 __attribute__((ext_vector_type(4)));
typedef float f32x4 __attribute__((ext_vector_type(4)));

#define NB 4096
#define KTOT 24576
#define NOUT 512
#define NCH 48

__device__ __forceinline__ short f2bf(float f){
  union { float f; uint32_t u; } x; x.f = f;
  uint32_t r = (x.u + 0x7FFFu + ((x.u >> 16) & 1u)) >> 16;
  return (short)r;
}
__device__ __forceinline__ float bf2f(short s){
  union { uint32_t u; float f; } x; x.u = ((uint32_t)(uint16_t)s) << 16;
  return x.f;
}
__device__ __forceinline__ short f2bf_fast(float x){
  union { __hip_bfloat16 h; short s; } c; c.h = __float2bfloat16(x); return c.s;
}

#define GLOAD16(g, l) __builtin_amdgcn_global_load_lds( \
  (const __attribute__((address_space(1))) void*)(g), \
  (__attribute__((address_space(3))) void*)(l), 16, 0, 0)

// ---------------- kernel 0: column->channel map + zero bn0 accumulators ----
__global__ __launch_bounds__(256) void k_colmap(const int* __restrict__ perm,
                                                int* __restrict__ chmap,
                                                float* __restrict__ statf){
  int q = blockIdx.x * 256 + threadIdx.x;
  if (q < 1024) chmap[perm[q]] = q >> 9;
  if (blockIdx.x == 0 && threadIdx.x < 4) statf[threadIdx.x] = 0.f;
}

// ---------------- kernel 1: bn0 batch stats (chmap hoisted) ---------------
__global__ __launch_bounds__(256) void k_bn0(const float* __restrict__ concat,
                                             const int* __restrict__ chmap,
                                             float* __restrict__ statf){
  int t = threadIdx.x;
  const int ch = chmap[(blockIdx.x*256 + t) & 1023];
  float s0=0,q0=0,s1=0,q1=0;
  for (int idx = blockIdx.x*256 + t; idx < NB*1024; idx += 2048*256){
    float v = concat[idx];
    if (ch){ s1 += v; q1 += v*v; } else { s0 += v; q0 += v*v; }
  }
  #pragma unroll
  for (int m=1;m<64;m<<=1){
    s0 += __shfl_xor(s0,m); q0 += __shfl_xor(q0,m);
    s1 += __shfl_xor(s1,m); q1 += __shfl_xor(q1,m);
  }
  __shared__ float lb[4][4];
  int wid = t>>6, lane = t&63;
  if (lane==0){ lb[wid][0]=s0; lb[wid][1]=q0; lb[wid][2]=s1; lb[wid][3]=q1; }
  __syncthreads();
  if (t==0){
    float a0=0,a1=0,a2=0,a3=0;
    #pragma unroll
    for (int w=0;w<4;w++){ a0+=lb[w][0]; a1+=lb[w][1]; a2+=lb[w][2]; a3+=lb[w][3]; }
    atomicAdd(&statf[0],a0); atomicAdd(&statf[1],a1);
    atomicAdd(&statf[2],a2); atomicAdd(&statf[3],a3);
  }
}

// ---- kernel 2: cast+transpose fc_W -> wT[n][k] bf16 (PLAIN layout) -------
__global__ __launch_bounds__(256) void k_wcast(const float* __restrict__ fcW,
                                               short* __restrict__ wT){
  __shared__ float tile[64][65];
  int bid = blockIdx.x;
  int kb = (bid % 384) * 64;
  int nb = (bid / 384) * 64;
  int t = threadIdx.x;
  #pragma unroll
  for (int i=0;i<16;i++){
    int r = i*4 + (t>>6), c = t & 63;
    tile[r][c] = fcW[(size_t)(kb + r)*NOUT + nb + c];
  }
  __syncthreads();
  #pragma unroll
  for (int i=0;i<16;i++){
    int n = i*4 + (t>>6), k = t & 63;
    wT[(size_t)(nb + n)*KTOT + kb + k] = f2bf(tile[k][n]);
  }
}

// ---------------- kernel 3: per-sample conv (3 branches) ------------------
__global__ __launch_bounds__(256) void k_conv(
    const float* __restrict__ concat, const int* __restrict__ perm,
    const int* __restrict__ rel,
    const float* __restrict__ f1t, const float* __restrict__ f3t,
    const float* __restrict__ f5t,
    const float* __restrict__ statf,
    const float* __restrict__ bn0g, const float* __restrict__ bn0b,
    short* __restrict__ raw, float* __restrict__ psum, float* __restrict__ psq)
{
  const int b = blockIdx.x;
  const int t = threadIdx.x;
  __shared__ float xn[2*9*9*9];     // padded [2][9][9][9], pad = 0
  __shared__ float filt[448];
  for (int i=t;i<1458;i+=256) xn[i]=0.f;
  int r = rel[b];
  for (int i=t;i<448;i+=256){
    float v;
    if (i < 64)       v = f1t[r*64 + i];
    else if (i < 192) v = f3t[r*128 + (i-64)];
    else              v = f5t[r*256 + (i-192)];
    filt[i]=v;
  }
  __syncthreads();
  const float n0inv = 1.f/(4096.f*512.f);
  float m0 = statf[0]*n0inv, e0 = statf[1]*n0inv;
  float m1 = statf[2]*n0inv, e1 = statf[3]*n0inv;
  float sc0 = bn0g[0]*rsqrtf(e0-m0*m0+1e-5f), sh0 = bn0b[0]-m0*sc0;
  float sc1 = bn0g[1]*rsqrtf(e1-m1*m1+1e-5f), sh1 = bn0b[1]-m1*sc1;
  for (int q=t;q<1024;q+=256){
    int col = perm[q];
    float v = concat[(size_t)b*1024 + col];
    int ch = q>>9, s = q & 511;
    int d = s>>6, h=(s>>3)&7, w=s&7;
    xn[ch*729 + d*81 + h*9 + w] = ch ? v*sc1+sh1 : v*sc0+sh0;
  }
  __syncthreads();

  const int wid = t>>6, lane = t&63;
  const int d = lane>>3, h = lane&7;
  float r00[9], r01[9], r10[9], r11[9], r20[9], r21[9], r30[9], r31[9];
  #pragma unroll
  for (int w9=0;w9<9;w9++){
    int base0 = d*81 + h*9 + w9;
    int base1 = d*81 + (h+1)*9 + w9;
    int base2 = (d+1)*81 + h*9 + w9;
    int base3 = (d+1)*81 + (h+1)*9 + w9;
    r00[w9]=xn[base0];      r01[w9]=xn[729+base0];
    r10[w9]=xn[base1];      r11[w9]=xn[729+base1];
    r20[w9]=xn[base2];      r21[w9]=xn[729+base2];
    r30[w9]=xn[base3];      r31[w9]=xn[729+base3];
  }
  const size_t rawbase = (size_t)b*KTOT;

  auto finish = [&](int c, const float* v){
    float s=0,q=0;
    #pragma unroll
    for (int p=0;p<8;p++){ s += v[p]; q += v[p]*v[p]; }
    #pragma unroll
    for (int m=1;m<64;m<<=1){ s += __shfl_xor(s,m); q += __shfl_xor(q,m); }
    if (lane==0){ psum[c*NB+b]=s; psq[c*NB+b]=q; }
    s16x8 pk;
    #pragma unroll
    for (int p=0;p<8;p++) pk[p] = f2bf_fast(v[p]);
    *reinterpret_cast<s16x8*>(raw + rawbase + (size_t)c*512 + lane*8) = pk;
  };

  #pragma unroll
  for (int i=0;i<4;i++){
    int oc = wid + 4*i;
    float c0=filt[oc*4+0], c1=filt[oc*4+1], c2=filt[oc*4+2], c3=filt[oc*4+3];
    float v[8];
    #pragma unroll
    for (int p=0;p<8;p++)
      v[p] = c0*r00[p]+c1*r00[p+1]+c2*r01[p]+c3*r01[p+1];
    finish(oc, v);
  }
  #pragma unroll
  for (int i=0;i<4;i++){
    int oc = wid + 4*i;
    const float* cf = &filt[64 + oc*8];
    float v[8];
    #pragma unroll
    for (int p=0;p<8;p++)
      v[p] = cf[0]*r00[p]+cf[1]*r00[p+1]+cf[2]*r10[p]+cf[3]*r10[p+1]
           + cf[4]*r01[p]+cf[5]*r01[p+1]+cf[6]*r11[p]+cf[7]*r11[p+1];
    finish(16+oc, v);
  }
  #pragma unroll
  for (int i=0;i<4;i++){
    int oc = wid + 4*i;
    const float* cf = &filt[192 + oc*16];
    float v[8];
    #pragma unroll
    for (int p=0;p<8;p++)
      v[p] = cf[0]*r00[p] +cf[1]*r00[p+1] +cf[2]*r10[p] +cf[3]*r10[p+1]
           + cf[4]*r20[p] +cf[5]*r20[p+1] +cf[6]*r30[p] +cf[7]*r30[p+1]
           + cf[8]*r01[p] +cf[9]*r01[p+1] +cf[10]*r11[p]+cf[11]*r11[p+1]
           + cf[12]*r21[p]+cf[13]*r21[p+1]+cf[14]*r31[p]+cf[15]*r31[p+1];
    finish(32+oc, v);
  }
}

// ---------------- kernel 4: finalize bn1/2/3 scale+shift ------------------
__global__ __launch_bounds__(256) void k_bnstats(
    const float* __restrict__ psum, const float* __restrict__ psq,
    const float* __restrict__ bn1g, const float* __restrict__ bn1b,
    const float* __restrict__ bn2g, const float* __restrict__ bn2b,
    const float* __restrict__ bn3g, const float* __restrict__ bn3b,
    float* __restrict__ statf)
{
  int c = blockIdx.x, t = threadIdx.x;
  float s=0,q=0;
  for (int b=t;b<NB;b+=256){ s += psum[c*NB+b]; q += psq[c*NB+b]; }
  #pragma unroll
  for (int m=1;m<64;m<<=1){ s += __shfl_xor(s,m); q += __shfl_xor(q,m); }
  __shared__ float lb[4][2];
  int wid = t>>6, lane = t&63;
  if (lane==0){ lb[wid][0]=s; lb[wid][1]=q; }
  __syncthreads();
  if (t==0){
    s = lb[0][0]+lb[1][0]+lb[2][0]+lb[3][0];
    q = lb[0][1]+lb[1][1]+lb[2][1]+lb[3][1];
    float n = 4096.f*512.f;
    float mean = s/n, var = q/n - mean*mean;
    const float* g  = c<16 ? bn1g : (c<32 ? bn2g : bn3g);
    const float* bb = c<16 ? bn1b : (c<32 ? bn2b : bn3b);
    int oc = c & 15;
    float sc = g[oc]*rsqrtf(var + 1e-5f);
    statf[16+c] = sc;
    statf[64+c] = bb[oc] - mean*sc;
  }
}

// ---------------- kernel 5: SE gates (thread-per-sample) ------------------
__global__ __launch_bounds__(256) void k_se(
    const float* __restrict__ psum, const float* __restrict__ statf,
    const float* __restrict__ Wsq, const float* __restrict__ bsq,
    const float* __restrict__ W1, const float* __restrict__ b1,
    const float* __restrict__ W2, const float* __restrict__ b2,
    const float* __restrict__ W3, const float* __restrict__ b3,
    float* __restrict__ gates)
{
  int b = blockIdx.x*256 + threadIdx.x;
  float pooled[16];
  #pragma unroll
  for (int oc=0;oc<16;oc++){
    float p = 0.f;
    #pragma unroll
    for (int br=0;br<3;br++){
      int c = br*16 + oc;
      p += psum[c*NB+b]*(1.f/512.f)*statf[16+c] + statf[64+c];
    }
    pooled[oc] = p;
  }
  float zq[32];
  #pragma unroll
  for (int r2=0;r2<32;r2++){
    float z = bsq[r2];
    #pragma unroll
    for (int oc=0;oc<16;oc++) z += pooled[oc]*Wsq[oc*32+r2];
    zq[r2] = fmaxf(z, 0.f);
  }
  #pragma unroll
  for (int br=0;br<3;br++){
    const float* W  = br==0 ? W1 : (br==1 ? W2 : W3);
    const float* bb = br==0 ? b1 : (br==1 ? b2 : b3);
    #pragma unroll
    for (int oc=0;oc<16;oc++){
      float g = bb[oc];
      #pragma unroll
      for (int r2=0;r2<32;r2++) g += zq[r2]*W[r2*16+oc];
      gates[(size_t)(br*16+oc)*NB + b] = 1.f/(1.f + expf(-g));
    }
  }
}

// ---------------- kernel 6: flatmm-style fused GEMM (split-K=8) -----------
// BM=128, BN=512, BK=32, 8 waves (2M x 4N, wave 64x128).
// A ring-5 LDS (stage s+4, 2-step confirmed flight), W ring-3 (stage s+2,
// 2-step L2 flight). ONE vmcnt(6) + ONE barrier per step, issues AFTER the
// barrier (race-proof). Swizzle: phys granule = g ^ ((row>>1)&3) -> bank
// group (row&1)*4 ^ g: uniform 8 groups, conflict-free b128.
// A transformed in-place in LDS (lane's own 16B), relu(raw*sc+sh)*gate.
__global__ __launch_bounds__(512, 2) void k_gemm(
    const short* __restrict__ raw, const short* __restrict__ wT,
    const float* __restrict__ scale, const float* __restrict__ shift,
    const float* __restrict__ gates, short* __restrict__ partials)
{
  const int t = threadIdx.x;
  const int bid = blockIdx.x;
  const int sk = bid & 7, mblk = bid >> 3;   // sk = XCD id -> W L2-resident
  const int b0 = mblk*128;
  const int kb0 = sk*3072;                   // 96 K-steps of 32

  __shared__ __align__(16) short Al[5][128*32];   // 8 KB per slot
  __shared__ __align__(16) short Wl[3][512*32];   // 32 KB per slot
  __shared__ float gscL[6*128], gshL[6*128];

  const int wid = t>>6, lane = t&63;
  const int wm = wid>>2, wn = wid&3;         // 2M x 4N
  const int fr = lane&15, kq = lane>>4;

  // ---- gate*scale / gate*shift table ----
  for (int i=t;i<768;i+=512){
    int c = i>>7, r = i&127;
    int ch = sk*6 + c;
    float g = gates[(size_t)ch*NB + b0 + r];
    gscL[i] = scale[ch]*g;
    gshL[i] = shift[ch]*g;
  }
  __syncthreads();   // drains all counters: clean vmcnt ledger

  // ---- staging (inverse-swizzled global source, linear LDS dest) ----
  const int row_t = wid*16 + (lane>>2);                 // A row this lane
  const int gsw = (((lane&3) ^ ((lane>>3)&3)))*8;       // swizzled granule
  const short* ap = raw + (size_t)(b0+row_t)*KTOT + kb0 + gsw;
  const short* wp0 = wT + (size_t)(wid*64 +  0 + (lane>>2))*KTOT + kb0 + gsw;
  const short* wp1 = wT + (size_t)(wid*64 + 16 + (lane>>2))*KTOT + kb0 + gsw;
  const short* wp2 = wT + (size_t)(wid*64 + 32 + (lane>>2))*KTOT + kb0 + gsw;
  const short* wp3 = wT + (size_t)(wid*64 + 48 + (lane>>2))*KTOT + kb0 + gsw;

  // ---- fragment read byte-offsets (swizzled ds_read) ----
  const int so16 = (kq ^ ((fr>>1)&3))<<4;
  int afb[4], bfb[8];
  #pragma unroll
  for (int m=0;m<4;m++) afb[m] = (wm*64 + m*16 + fr)*64 + so16;
  #pragma unroll
  for (int n=0;n<8;n++) bfb[n] = (wn*128 + n*16 + fr)*64 + so16;

  f32x4 acc[4][8];
  #pragma unroll
  for (int m=0;m<4;m++)
    #pragma unroll
    for (int n=0;n<8;n++){ f32x4 z = {0.f,0.f,0.f,0.f}; acc[m][n]=z; }

  #define STAGE_W(sl, ko_) { \
    GLOAD16(wp0 + (ko_), &Wl[sl][(wid*64 +  0)*32]); \
    GLOAD16(wp1 + (ko_), &Wl[sl][(wid*64 + 16)*32]); \
    GLOAD16(wp2 + (ko_), &Wl[sl][(wid*64 + 32)*32]); \
    GLOAD16(wp3 + (ko_), &Wl[sl][(wid*64 + 48)*32]); }
  #define STAGE_A(sl, ko_)  GLOAD16(ap + (ko_), &Al[sl][wid*512])

  #define XF(sl, tl) { \
    int ch_ = (tl)>>4; ch_ = ch_>5 ? 5 : ch_; \
    float sc_ = gscL[ch_*128 + row_t], sh_ = gshL[ch_*128 + row_t]; \
    short* p_ = &Al[sl][wid*512 + lane*8]; \
    s16x8 v_ = *reinterpret_cast<const s16x8*>(p_); \
    s16x8 o_; \
    _Pragma("unroll") \
    for (int j_=0;j_<8;j_++) o_[j_] = f2bf_fast(fmaxf(bf2f(v_[j_])*sc_+sh_, 0.f)); \
    *reinterpret_cast<s16x8*>(p_) = o_; }

  #define LGKM0 asm volatile("s_waitcnt lgkmcnt(0)" ::: "memory")

  // ---- prologue: A0,A1 | W0,A2 | W1,A3  (12 loads) ----
  STAGE_A(0, 0);  STAGE_A(1, 32);
  STAGE_W(0, 0);  STAGE_A(2, 64);
  STAGE_W(1, 32); STAGE_A(3, 96);
  asm volatile("s_waitcnt vmcnt(10)" ::: "memory");   // A0, A1 landed
  XF(0, 0);
  LGKM0;

  int sl_r = 0, sl_x = 1, sl_a = 4;    // A: read s%5, xf (s+1)%5, stage (s+4)%5
  int sw_r = 0, sw_s = 2;              // W: read s%3, stage (s+2)%3
  for (int s = 0; s < 96; ++s){
    asm volatile("s_waitcnt vmcnt(6)" ::: "memory");   // W(s), A(s+1) landed
    __builtin_amdgcn_s_barrier();
    __builtin_amdgcn_sched_barrier(0);
    // stage W(s+2), A(s+4)  (slots were last read at step s-1: safe)
    STAGE_W(sw_s, (s+2)*32);
    STAGE_A(sl_a, (s+4)*32);
    // fragments
    const char* Ab = (const char*)Al[sl_r];
    const char* Wb = (const char*)Wl[sw_r];
    s16x8 af[4], bf[8];
    #pragma unroll
    for (int m=0;m<4;m++) af[m] = *reinterpret_cast<const s16x8*>(Ab + afb[m]);
    #pragma unroll
    for (int n=0;n<8;n++) bf[n] = *reinterpret_cast<const s16x8*>(Wb + bfb[n]);
    __builtin_amdgcn_s_setprio(1);
    #pragma unroll
    for (int m=0;m<4;m++)
      #pragma unroll
      for (int n=0;n<8;n++)
        acc[m][n] = __builtin_amdgcn_mfma_f32_16x16x32_bf16(af[m], bf[n], acc[m][n], 0,0,0);
    __builtin_amdgcn_s_setprio(0);
    // transform next A tile in place (own 16B per lane)
    XF(sl_x, s+1);
    LGKM0;
    // rotate slots
    sl_r = sl_x; sl_x = (sl_x==4)?0:sl_x+1; sl_a = (sl_a==4)?0:sl_a+1;
    sw_r = (sw_r==2)?0:sw_r+1; sw_s = (sw_s==2)?0:sw_s+1;
  }

  // ---- epilogue: bf16 partials [sk][4096][512] ----
  short* pb = partials + (size_t)sk*NB*NOUT;
  #pragma unroll
  for (int m=0;m<4;m++){
    #pragma unroll
    for (int j=0;j<4;j++){
      int row = b0 + wm*64 + m*16 + kq*4 + j;
      short* prow = pb + (size_t)row*NOUT + wn*128 + fr;
      #pragma unroll
      for (int n=0;n<8;n++) prow[n*16] = f2bf_fast(acc[m][n][j]);
    }
  }
  #undef STAGE_W
  #undef STAGE_A
  #undef XF
  #undef LGKM0
}

// ---------------- kernel 7: split-K reduce + bias -------------------------
__global__ __launch_bounds__(256) void k_red(const short* __restrict__ partials,
                                             const float* __restrict__ fcb,
                                             float* __restrict__ out){
  int i = blockIdx.x*256 + threadIdx.x;          // 524288 threads, 4 outs each
  int base = i*4;
  f32x4 v = *reinterpret_cast<const f32x4*>(fcb + (base & 511));
  #pragma unroll
  for (int sk=0;sk<8;sk++){
    s16x4 p = *reinterpret_cast<const s16x4*>(partials + (size_t)sk*2097152 + base);
    v[0] += bf2f(p[0]); v[1] += bf2f(p[1]);
    v[2] += bf2f(p[2]); v[3] += bf2f(p[3]);
  }
  *reinterpret_cast<f32x4*>(out + base) = v;
}

// ---------------- launch ---------------------------------------------------
extern "C" void kernel_launch(void* const* d_in, const int* in_sizes, int n_in,
                              void* d_out, int out_size, void* d_ws, size_t ws_size,
                              hipStream_t stream) {
  const float* concat = (const float*)d_in[0];
  const int*   rel    = (const int*)  d_in[1];
  const int*   perm   = (const int*)  d_in[2];
  const float* f1t = (const float*)d_in[3];
  const float* f3t = (const float*)d_in[4];
  const float* f5t = (const float*)d_in[5];
  const float* bn0g=(const float*)d_in[6],  *bn0b=(const float*)d_in[7];
  const float* bn1g=(const float*)d_in[8],  *bn1b=(const float*)d_in[9];
  const float* bn2g=(const float*)d_in[10], *bn2b=(const float*)d_in[11];
  const float* bn3g=(const float*)d_in[12], *bn3b=(const float*)d_in[13];
  const float* Wsq=(const float*)d_in[14],  *bsq=(const float*)d_in[15];
  const float* W1=(const float*)d_in[16],   *b1=(const float*)d_in[17];
  const float* W2=(const float*)d_in[18],   *b2=(const float*)d_in[19];
  const float* W3=(const float*)d_in[20],   *b3=(const float*)d_in[21];
  const float* fcW=(const float*)d_in[22],  *fcb=(const float*)d_in[23];
  float* out = (float*)d_out;
  char* ws = (char*)d_ws;

  const size_t off_raw  = 0;                         // 4096*24576*2 = 201326592
  const size_t off_wT   = 201326592;                 // 512*24576*2  = 25165824
  const size_t off_part = 226492416;                 // 8*4096*512*2 = 33554432 (bf16)
  const size_t off_psum = 260046848;                 // 48*4096*4    = 786432
  const size_t off_psq  = 260833280;                 // 786432
  const size_t off_gate = 261619712;                 // 786432
  const size_t off_stat = 262406144;                 // 512
  const size_t off_chm  = 262406656;                 // 4096
  const size_t need     = off_chm + 4096;
  if (ws_size < need) return;  // diagnose: output stays zero -> absmax ~2.86

  short* raw      = (short*)(ws + off_raw);
  short* wT       = (short*)(ws + off_wT);
  short* partials = (short*)(ws + off_part);
  float* psum     = (float*)(ws + off_psum);
  float* psq      = (float*)(ws + off_psq);
  float* gates    = (float*)(ws + off_gate);
  float* statf    = (float*)(ws + off_stat);
  int*   chmap    = (int*)  (ws + off_chm);

  k_colmap<<<4, 256, 0, stream>>>(perm, chmap, statf);
  k_bn0   <<<2048, 256, 0, stream>>>(concat, chmap, statf);
  k_wcast <<<3072, 256, 0, stream>>>(fcW, wT);
  k_conv  <<<4096, 256, 0, stream>>>(concat, perm, rel, f1t, f3t, f5t,
                                     statf, bn0g, bn0b, raw, psum, psq);
  k_bnstats<<<48, 256, 0, stream>>>(psum, psq, bn1g, bn1b, bn2g, bn2b,
                                    bn3g, bn3b, statf);
  k_se    <<<16, 256, 0, stream>>>(psum, statf, Wsq, bsq, W1, b1, W2, b2,
                                   W3, b3, gates);
  k_gemm  <<<256, 512, 0, stream>>>(raw, wT, statf+16, statf+64, gates, partials);
  k_red   <<<2048, 256, 0, stream>>>(partials, fcb, out);
}